// Round 10
// baseline (641.261 us; speedup 1.0000x reference)
//
#include <hip/hip_runtime.h>
#include <hip/hip_fp16.h>
#include <math.h>

#define NLEV 16
#define TBLN (1u << 19)
#define TMASK (TBLN - 1u)
#define NPT 4             // consecutive points per thread in fused level kernel
#define NPTL 16           // points per thread in LDS level kernels
#define PR1 2654435761u
#define PR2 805459861u

typedef float f32x4 __attribute__((ext_vector_type(4)));
typedef unsigned int u32;
typedef unsigned int u32x2 __attribute__((ext_vector_type(2)));
typedef unsigned int u32x4 __attribute__((ext_vector_type(4)));

struct ScaleArgs { float s[NLEV]; };

// ---- compile-time geometry (scales fixed: 16,21.7,29.4,39.8,53.9,73.0,...) ----
// LDS levels 0,1: unpaired u32 grids D^3
#define DU0 18
#define DU1 23
#define GU0 0
#define GU1 5832            /* 18^3 */
#define GUTOT 17999         /* + 23^3 */
// L2 dense levels 2..5: x-pair-duplicated grids (D-1)*D*D of u32x2
#define DD2 31
#define DD3 41
#define DD4 55
#define DD5 75
#define GO2 0
#define GO3 28830           /* 30*31*31 */
#define GO4 96070           /* +40*41*41 */
#define GO5 259420          /* +54*55*55 */
#define GPTOT 675670        /* +74*75*75 */

static __device__ __forceinline__ u32 packf2(float a, float b) {
    __half2 h = __floats2half2_rn(a, b);          // low16 = a, high16 = b
    return __builtin_bit_cast(u32, h);
}
static __device__ __forceinline__ float2 unpack16(u32 u) {
    __half2 h = __builtin_bit_cast(__half2, u);
    return __half22float2(h);                      // .x = low half
}

// W f32 (levels 6..15) -> packed fp16 pairs, one u32 per table entry
__global__ __launch_bounds__(256)
void convert_w(const float* __restrict__ W, u32* __restrict__ Wh, int np4)
{
    int i = blockIdx.x * blockDim.x + threadIdx.x;
    if (i >= np4) return;
    const f32x4* src = reinterpret_cast<const f32x4*>(W) + (size_t)i * 2;
    f32x4 A = __builtin_nontemporal_load(src);
    f32x4 B = __builtin_nontemporal_load(src + 1);
    u32x4 o = { packf2(A.x, A.y), packf2(A.z, A.w),
                packf2(B.x, B.y), packf2(B.z, B.w) };
    __builtin_nontemporal_store(o, reinterpret_cast<u32x4*>(Wh) + i);
}

// unpaired dense grid G[iz][iy][ix] (stride D), from f32 W, bit-identical pack
__global__ __launch_bounds__(256)
void build_unpaired(const float* __restrict__ Wlf, u32* __restrict__ Gu, int D, int P)
{
    int v = blockIdx.x * blockDim.x + threadIdx.x;
    if (v >= P) return;
    int ix = v % D;
    int rest = v / D;
    int iy = rest % D;
    int iz = rest / D;
    u32 h = (((u32)iy * PR1) ^ ((u32)iz * PR2) ^ (u32)ix) & TMASK;
    float2 f = *reinterpret_cast<const float2*>(Wlf + (size_t)h * 2u);
    Gu[v] = packf2(f.x, f.y);
}

// x-pair-duplicated grid Gp[(iz*D+iy)*(D-1)+ix] = (pack(W[h(ix)]), pack(W[h(ix+1)]))
__global__ __launch_bounds__(256)
void build_dense(const float* __restrict__ Wlf, u32x2* __restrict__ Gpl, int D, int P)
{
    int v = blockIdx.x * blockDim.x + threadIdx.x;
    if (v >= P) return;
    int Dx = D - 1;
    int ix = v % Dx;
    int rest = v / Dx;
    int iy = rest % D;
    int iz = rest / D;
    u32 e = ((u32)iy * PR1) ^ ((u32)iz * PR2);
    u32 h0 = (e ^ (u32)ix) & TMASK;
    u32 h1 = (e ^ (u32)(ix + 1)) & TMASK;
    float2 f0 = *reinterpret_cast<const float2*>(Wlf + (size_t)h0 * 2u);
    float2 f1 = *reinterpret_cast<const float2*>(Wlf + (size_t)h1 * 2u);
    u32x2 o = { packf2(f0.x, f0.y), packf2(f1.x, f1.y) };
    Gpl[v] = o;
}

// ---- consecutive 4-point x load / scratch store helpers ----
// n0 = 4t -> x byte offset 48t (16B aligned): 3 NT dwordx4 per thread,
// 12 line-requests/wave/level instead of 36 (scalar strided loads).
static __device__ __forceinline__ void load4pts(
    const float* __restrict__ x, int n0, int N,
    float (&px)[NPT], float (&py)[NPT], float (&pz)[NPT])
{
    if (n0 + NPT <= N) {
        const f32x4* p = reinterpret_cast<const f32x4*>(x + (size_t)n0 * 3);
        f32x4 A = __builtin_nontemporal_load(p);
        f32x4 B = __builtin_nontemporal_load(p + 1);
        f32x4 C = __builtin_nontemporal_load(p + 2);
        px[0] = A.x; py[0] = A.y; pz[0] = A.z;
        px[1] = A.w; py[1] = B.x; pz[1] = B.y;
        px[2] = B.z; py[2] = B.w; pz[2] = C.x;
        px[3] = C.y; py[3] = C.z; pz[3] = C.w;
    } else {
        #pragma unroll
        for (int i = 0; i < NPT; ++i) {
            int n = n0 + i; if (n > N - 1) n = N - 1;
            px[i] = x[(size_t)n * 3 + 0];
            py[i] = x[(size_t)n * 3 + 1];
            pz[i] = x[(size_t)n * 3 + 2];
        }
    }
}

static __device__ __forceinline__ void store4(u32* __restrict__ scl, int n0, int N,
                                              const u32 (&r)[NPT])
{
    if (n0 + NPT <= N) {
        u32x4 v = { r[0], r[1], r[2], r[3] };
        __builtin_nontemporal_store(v, reinterpret_cast<u32x4*>(scl + n0));
    } else {
        #pragma unroll
        for (int i = 0; i < NPT; ++i)
            if (n0 + i < N) scl[n0 + i] = r[i];
    }
}

// ---- LDS level kernel (levels 0,1): grid in static LDS; zero L2 gather slots ----
template<int D>
__global__ __launch_bounds__(256)
void lds_level(const float* __restrict__ x, const u32* __restrict__ Gu,
               u32* __restrict__ scl, float scale, int N)
{
    __shared__ u32 g[D * D * D];
    for (int i = threadIdx.x; i < D * D * D; i += 256) g[i] = Gu[i];
    __syncthreads();

    int base = blockIdx.x * (256 * NPTL);
    #pragma unroll 4
    for (int i = 0; i < NPTL; ++i) {
        int n = base + i * 256 + (int)threadIdx.x;
        if (n < N) {
            float px = __builtin_nontemporal_load(&x[(size_t)n * 3 + 0]);
            float py = __builtin_nontemporal_load(&x[(size_t)n * 3 + 1]);
            float pz = __builtin_nontemporal_load(&x[(size_t)n * 3 + 2]);
            float ux = px * scale, uy = py * scale, uz = pz * scale;
            int ix = (int)ux, iy = (int)uy, iz = (int)uz;
            float dx = ux - (float)ix, dy = uy - (float)iy, dz = uz - (float)iz;
            int b = (iz * D + iy) * D + ix;
            u32 c0 = g[b],             c1 = g[b + 1];
            u32 c2 = g[b + D],         c3 = g[b + D + 1];
            u32 c4 = g[b + D * D],     c5 = g[b + D * D + 1];
            u32 c6 = g[b + D * D + D], c7 = g[b + D * D + D + 1];
            float wxl = 1.f - dx, wxh = dx;
            float wyl = 1.f - dy, wyh = dy;
            float wzl = 1.f - dz, wzh = dz;
            float ax = 0.f, ay = 0.f;
            float2 f;
            f = unpack16(c0); { float w = (wxl * wyl) * wzl; ax = fmaf(f.x, w, ax); ay = fmaf(f.y, w, ay); }
            f = unpack16(c1); { float w = (wxh * wyl) * wzl; ax = fmaf(f.x, w, ax); ay = fmaf(f.y, w, ay); }
            f = unpack16(c2); { float w = (wxl * wyh) * wzl; ax = fmaf(f.x, w, ax); ay = fmaf(f.y, w, ay); }
            f = unpack16(c3); { float w = (wxh * wyh) * wzl; ax = fmaf(f.x, w, ax); ay = fmaf(f.y, w, ay); }
            f = unpack16(c4); { float w = (wxl * wyl) * wzh; ax = fmaf(f.x, w, ax); ay = fmaf(f.y, w, ay); }
            f = unpack16(c5); { float w = (wxh * wyl) * wzh; ax = fmaf(f.x, w, ax); ay = fmaf(f.y, w, ay); }
            f = unpack16(c6); { float w = (wxl * wyh) * wzh; ax = fmaf(f.x, w, ax); ay = fmaf(f.y, w, ay); }
            f = unpack16(c7); { float w = (wxh * wyh) * wzh; ax = fmaf(f.x, w, ax); ay = fmaf(f.y, w, ay); }
            __builtin_nontemporal_store(packf2(ax, ay), scl + n);
        }
    }
}

// ---- fused-kernel per-level bodies (lvl is block-uniform) ----

// L2-dense: exactly 4 aligned 8B gathers per point
template<int D>
static __device__ __forceinline__ void dense_body(
    const float* __restrict__ x, const u32x2* __restrict__ Gp,
    u32* __restrict__ scl, float scale, int N, int t)
{
    constexpr int Dx = D - 1;
    constexpr int zstep = D * Dx;
    int n0 = t * NPT;

    float px[NPT], py[NPT], pz[NPT];
    load4pts(x, n0, N, px, py, pz);

    float dx[NPT], dy[NPT], dz[NPT];
    int base[NPT];
    u32x2 P0[NPT], P1[NPT], P2[NPT], P3[NPT];

    #pragma unroll
    for (int i = 0; i < NPT; ++i) {
        float ux = px[i] * scale, uy = py[i] * scale, uz = pz[i] * scale;
        int ix = (int)ux, iy = (int)uy, iz = (int)uz;   // trunc == floor (x>=0)
        dx[i] = ux - (float)ix;
        dy[i] = uy - (float)iy;
        dz[i] = uz - (float)iz;
        base[i] = (iz * D + iy) * Dx + ix;
    }

    #pragma unroll
    for (int i = 0; i < NPT; ++i) {
        int b = base[i];
        P0[i] = Gp[b];                 // corners v0,v1 (iy, iz)
        P1[i] = Gp[b + Dx];            // v2,v3 (iy+1, iz)
        P2[i] = Gp[b + zstep];         // v4,v5 (iy, iz+1)
        P3[i] = Gp[b + zstep + Dx];    // v6,v7 (iy+1, iz+1)
    }

    u32 r[NPT];
    #pragma unroll
    for (int i = 0; i < NPT; ++i) {
        float ax = 0.f, ay = 0.f;
        float wxl = 1.f - dx[i], wxh = dx[i];
        float wyl = 1.f - dy[i], wyh = dy[i];
        float wzl = 1.f - dz[i], wzh = dz[i];
        {
            float2 f0 = unpack16(P0[i].x), f1 = unpack16(P0[i].y);
            float w0 = (wxl * wyl) * wzl, w1 = (wxh * wyl) * wzl;
            ax = fmaf(f0.x, w0, ax); ay = fmaf(f0.y, w0, ay);
            ax = fmaf(f1.x, w1, ax); ay = fmaf(f1.y, w1, ay);
        }
        {
            float2 f0 = unpack16(P1[i].x), f1 = unpack16(P1[i].y);
            float w0 = (wxl * wyh) * wzl, w1 = (wxh * wyh) * wzl;
            ax = fmaf(f0.x, w0, ax); ay = fmaf(f0.y, w0, ay);
            ax = fmaf(f1.x, w1, ax); ay = fmaf(f1.y, w1, ay);
        }
        {
            float2 f0 = unpack16(P2[i].x), f1 = unpack16(P2[i].y);
            float w0 = (wxl * wyl) * wzh, w1 = (wxh * wyl) * wzh;
            ax = fmaf(f0.x, w0, ax); ay = fmaf(f0.y, w0, ay);
            ax = fmaf(f1.x, w1, ax); ay = fmaf(f1.y, w1, ay);
        }
        {
            float2 f0 = unpack16(P3[i].x), f1 = unpack16(P3[i].y);
            float w0 = (wxl * wyh) * wzh, w1 = (wxh * wyh) * wzh;
            ax = fmaf(f0.x, w0, ax); ay = fmaf(f0.y, w0, ay);
            ax = fmaf(f1.x, w1, ax); ay = fmaf(f1.y, w1, ay);
        }
        r[i] = packf2(ax, ay);
    }
    store4(scl, n0, N, r);
}

// hash: even-ix u32x2 pairing, avg 6 8B-requests/pt
static __device__ __forceinline__ void hash_body(
    const float* __restrict__ x, const u32* __restrict__ Wl,
    u32* __restrict__ scl, float scale, int N, int t)
{
    int n0 = t * NPT;

    float px[NPT], py[NPT], pz[NPT];
    load4pts(x, n0, N, px, py, pz);

    float dx[NPT], dy[NPT], dz[NPT];
    u32 a0[NPT], a1[NPT], a2[NPT];
    u32 fv[NPT][8];

    #pragma unroll
    for (int i = 0; i < NPT; ++i) {
        float ux = px[i] * scale, uy = py[i] * scale, uz = pz[i] * scale;
        int ix = (int)ux, iy = (int)uy, iz = (int)uz;
        dx[i] = ux - (float)ix;
        dy[i] = uy - (float)iy;
        dz[i] = uz - (float)iz;
        a0[i] = (unsigned)ix;
        a1[i] = (unsigned)iy * PR1;
        a2[i] = (unsigned)iz * PR2;
    }

    #pragma unroll
    for (int i = 0; i < NPT; ++i) {
        u32 b0 = a0[i] + 1u, b1 = a1[i] + PR1, b2 = a2[i] + PR2;
        u32 E[4] = { a1[i] ^ a2[i], b1 ^ a2[i], a1[i] ^ b2, b1 ^ b2 };
        if ((a0[i] & 1u) == 0u) {
            #pragma unroll
            for (int j = 0; j < 4; ++j) {
                u32 hl = (E[j] ^ a0[i]) & TMASK;       // h_hi = hl ^ 1
                u32x2 p = *reinterpret_cast<const u32x2*>(Wl + (hl & ~1u));
                u32 lo = (hl & 1u) ? p.y : p.x;
                u32 hi = (hl & 1u) ? p.x : p.y;
                fv[i][2 * j + 0] = lo;
                fv[i][2 * j + 1] = hi;
            }
        } else {
            #pragma unroll
            for (int j = 0; j < 4; ++j) {
                u32 hl = (E[j] ^ a0[i]) & TMASK;
                u32 hh = (E[j] ^ b0) & TMASK;
                fv[i][2 * j + 0] = Wl[hl];
                fv[i][2 * j + 1] = Wl[hh];
            }
        }
    }

    u32 r[NPT];
    #pragma unroll
    for (int i = 0; i < NPT; ++i) {
        float ax = 0.f, ay = 0.f;
        #pragma unroll
        for (int v = 0; v < 8; ++v) {
            float wx = (v & 1) ? dx[i] : 1.f - dx[i];
            float wy = (v & 2) ? dy[i] : 1.f - dy[i];
            float wz = (v & 4) ? dz[i] : 1.f - dz[i];
            float w = (wx * wy) * wz;
            float2 f = unpack16(fv[i][v]);
            ax = fmaf(f.x, w, ax);
            ay = fmaf(f.y, w, ay);
        }
        r[i] = packf2(ax, ay);
    }
    store4(scl, n0, N, r);
}

// Fused kernel for levels 2..15 (level-major block order keeps one-table L2 locality)
__global__ __launch_bounds__(256)
void fused_levels(const float* __restrict__ x, const u32* __restrict__ Wh,
                  const u32x2* __restrict__ Gp, u32* __restrict__ scratch,
                  ScaleArgs sc, int N, int TOT, int BPL)
{
    int li = blockIdx.x / BPL;          // 0..13
    int lvl = li + 2;
    int t = (blockIdx.x - li * BPL) * blockDim.x + threadIdx.x;
    if (t >= TOT) return;
    float scale = sc.s[lvl];
    u32* scl = scratch + (size_t)lvl * (size_t)N;

    switch (lvl) {   // block-uniform
        case 2: dense_body<DD2>(x, Gp + GO2, scl, scale, N, t); break;
        case 3: dense_body<DD3>(x, Gp + GO3, scl, scale, N, t); break;
        case 4: dense_body<DD4>(x, Gp + GO4, scl, scale, N, t); break;
        case 5: dense_body<DD5>(x, Gp + GO5, scl, scale, N, t); break;
        default:
            hash_body(x, Wh + (size_t)(lvl - 6) * TBLN, scl, scale, N, t);
            break;
    }
}

// LDS-staged transpose: load 256 pts x 16 levels coalesced, emit 1KB-contiguous
// full-line NT stores per wave.
__global__ __launch_bounds__(256)
void transpose_kernel(const u32* __restrict__ sc, float* __restrict__ out, int N)
{
    __shared__ u32 lds[16][257];
    int P0 = blockIdx.x * 256;
    int t = threadIdx.x;
    #pragma unroll
    for (int l = 0; l < NLEV; ++l) {
        int n = P0 + t;
        if (n < N) lds[l][t] = __builtin_nontemporal_load(sc + (size_t)l * N + n);
    }
    __syncthreads();
    int w = t >> 6, l6 = t & 63;
    #pragma unroll
    for (int k = 0; k < 8; ++k) {
        int p = w * 64 + k * 8 + (l6 >> 3);
        int c = l6 & 7;                       // chunk covers levels 2c, 2c+1
        if (P0 + p < N) {
            float2 f0 = unpack16(lds[2 * c][p]);
            float2 f1 = unpack16(lds[2 * c + 1][p]);
            f32x4 v = { f0.x, f0.y, f1.x, f1.y };
            __builtin_nontemporal_store(v,
                reinterpret_cast<f32x4*>(out + (size_t)(P0 + p) * 32u + (size_t)c * 4u));
        }
    }
}

// ---------------- fallback (round-1 kernel, known-good, f32 exact) ----------
__global__ __launch_bounds__(256)
void hashenc_fallback(const float* __restrict__ x, const float* __restrict__ W,
                      float* __restrict__ out, ScaleArgs sc, int N)
{
    int n = blockIdx.x * blockDim.x + threadIdx.x;
    if (n >= N) return;
    float px = x[(size_t)n * 3 + 0];
    float py = x[(size_t)n * 3 + 1];
    float pz = x[(size_t)n * 3 + 2];
    float acc[2 * NLEV];
    #pragma unroll
    for (int l = 0; l < NLEV; ++l) {
        float s = sc.s[l];
        float ux = px * s, uy = py * s, uz = pz * s;
        int ix = (int)ux, iy = (int)uy, iz = (int)uz;
        float dx = ux - (float)ix, dy = uy - (float)iy, dz = uz - (float)iz;
        unsigned a0 = (unsigned)ix;
        unsigned a1 = (unsigned)iy * PR1;
        unsigned a2 = (unsigned)iz * PR2;
        unsigned b0 = a0 + 1u, b1 = a1 + PR1, b2 = a2 + PR2;
        const float* Wl = W + (size_t)l * TBLN * 2u;
        float ax = 0.f, ay = 0.f;
        #pragma unroll
        for (int v = 0; v < 8; ++v) {
            unsigned h = ((v & 1) ? b0 : a0) ^ ((v & 2) ? b1 : a1) ^ ((v & 4) ? b2 : a2);
            h &= TMASK;
            float wx = (v & 1) ? dx : 1.f - dx;
            float wy = (v & 2) ? dy : 1.f - dy;
            float wz = (v & 4) ? dz : 1.f - dz;
            float w = (wx * wy) * wz;
            const float2 fvv = *reinterpret_cast<const float2*>(Wl + (size_t)h * 2u);
            ax = fmaf(fvv.x, w, ax);
            ay = fmaf(fvv.y, w, ay);
        }
        acc[2 * l + 0] = ax;
        acc[2 * l + 1] = ay;
    }
    float4* o = reinterpret_cast<float4*>(out + (size_t)n * (2 * NLEV));
    #pragma unroll
    for (int j = 0; j < 8; ++j)
        o[j] = make_float4(acc[4 * j + 0], acc[4 * j + 1], acc[4 * j + 2], acc[4 * j + 3]);
}

extern "C" void kernel_launch(void* const* d_in, const int* in_sizes, int n_in,
                              void* d_out, int out_size, void* d_ws, size_t ws_size,
                              hipStream_t stream) {
    const float* x = (const float*)d_in[0];
    const float* W = (const float*)d_in[1];
    float* out = (float*)d_out;
    int N = in_sizes[0] / 3;

    // numpy-exact scales
    ScaleArgs sc;
    double b = exp((log(2048.0) - log(16.0)) / 16.0);
    for (int l = 0; l < NLEV; ++l) {
        double p;
        switch (l) {
            case 0: p = 1.0; break;
            case 1: p = b;   break;
            case 2: p = b * b; break;
            default: p = pow(b, (double)l); break;
        }
        sc.s[l] = (float)(16.0 * p);
    }

    // workspace layout (u32 units): [Wh 10 tables][Gp paired 2..5][Gu 0,1][scratch]
    size_t wh_u32 = (size_t)(NLEV - 6) * TBLN;        // 21.0 MB
    size_t gp_u32 = (size_t)GPTOT * 2u;               // 5.4 MB
    size_t gu_u32 = (size_t)GUTOT;                    // 72 KB
    size_t scr_u32 = (size_t)NLEV * (size_t)N;        // 128 MB
    size_t need = (wh_u32 + gp_u32 + gu_u32 + scr_u32) * sizeof(u32);  // ~154.5 MB

    if (ws_size >= need) {
        u32* Wh = (u32*)d_ws;
        u32x2* Gp = reinterpret_cast<u32x2*>(Wh + wh_u32);
        u32* Gu = Wh + wh_u32 + gp_u32;
        u32* scratch = Gu + gu_u32;

        // fp16 tables for hash levels 6..15
        int np4 = (int)(wh_u32 / 4);
        hipLaunchKernelGGL(convert_w, dim3((np4 + 255) / 256), dim3(256), 0, stream,
                           W + (size_t)6 * TBLN * 2u, Wh, np4);

        // unpaired LDS grids for levels 0,1
        {
            int P0c = DU0 * DU0 * DU0;
            hipLaunchKernelGGL(build_unpaired, dim3((P0c + 255) / 256), dim3(256), 0, stream,
                               W + 0, Gu + GU0, DU0, P0c);
            int P1c = DU1 * DU1 * DU1;
            hipLaunchKernelGGL(build_unpaired, dim3((P1c + 255) / 256), dim3(256), 0, stream,
                               W + (size_t)1 * TBLN * 2u, Gu + GU1, DU1, P1c);
        }

        // paired grids for levels 2..5
        const int Dl[4] = { DD2, DD3, DD4, DD5 };
        const int Ol[4] = { GO2, GO3, GO4, GO5 };
        for (int i = 0; i < 4; ++i) {
            int l = 2 + i;
            int P = (Dl[i] - 1) * Dl[i] * Dl[i];
            hipLaunchKernelGGL(build_dense, dim3((P + 255) / 256), dim3(256), 0, stream,
                               W + (size_t)l * TBLN * 2u, Gp + Ol[i], Dl[i], P);
        }

        // levels 0,1 via LDS-resident grids (zero L2 gather slots)
        {
            int blocks = (N + 256 * NPTL - 1) / (256 * NPTL);
            hipLaunchKernelGGL(lds_level<DU0>, dim3(blocks), dim3(256), 0, stream,
                               x, Gu + GU0, scratch + 0, sc.s[0], N);
            hipLaunchKernelGGL(lds_level<DU1>, dim3(blocks), dim3(256), 0, stream,
                               x, Gu + GU1, scratch + (size_t)N, sc.s[1], N);
        }

        // levels 2..15 fused (level-major, consecutive 4-pt batching)
        int TOT = (N + NPT - 1) / NPT;
        int BPL = (TOT + 255) / 256;
        hipLaunchKernelGGL(fused_levels, dim3(14 * BPL), dim3(256), 0, stream,
                           x, Wh, Gp, scratch, sc, N, TOT, BPL);

        int gt = (N + 255) / 256;
        hipLaunchKernelGGL(transpose_kernel, dim3(gt), dim3(256), 0, stream,
                           scratch, out, N);
    } else {
        int grid = (N + 255) / 256;
        hipLaunchKernelGGL(hashenc_fallback, dim3(grid), dim3(256), 0, stream,
                           x, W, out, sc, N);
    }
}

// Round 11
// 627.257 us; speedup vs baseline: 1.0223x; 1.0223x over previous
//
#include <hip/hip_runtime.h>
#include <hip/hip_fp16.h>
#include <math.h>

#define NLEV 16
#define TBLN (1u << 19)
#define TMASK (TBLN - 1u)
#define NPT 4             // points per thread in fused level kernel (strided)
#define NPTL 16           // points per thread in static LDS level kernels
#define NPTL2 8           // points per thread in dynamic LDS level-2 kernel
#define PR1 2654435761u
#define PR2 805459861u

typedef float f32x4 __attribute__((ext_vector_type(4)));
typedef unsigned int u32;
typedef unsigned int u32x2 __attribute__((ext_vector_type(2)));
typedef unsigned int u32x4 __attribute__((ext_vector_type(4)));

struct ScaleArgs { float s[NLEV]; };

// ---- compile-time geometry (scales fixed: 16,21.7,29.4,39.8,53.9,73.0,...) ----
// LDS levels 0,1,2: unpaired u32 grids D^3 (level 2 via dynamic LDS, 119KB)
#define DU0 18
#define DU1 23
#define DU2 31
#define GU0 0
#define GU1 5832            /* 18^3 */
#define GU2 17999           /* + 23^3 */
#define GUTOT 47790         /* + 31^3 */
// L2 dense levels 2..5: x-pair-duplicated grids (D-1)*D*D of u32x2
// (level 2 grid kept as fallback if dynamic-LDS attribute fails)
#define DD2 31
#define DD3 41
#define DD4 55
#define DD5 75
#define GO2 0
#define GO3 28830           /* 30*31*31 */
#define GO4 96070           /* +40*41*41 */
#define GO5 259420          /* +54*55*55 */
#define GPTOT 675670        /* +74*75*75 */

static __device__ __forceinline__ u32 packf2(float a, float b) {
    __half2 h = __floats2half2_rn(a, b);          // low16 = a, high16 = b
    return __builtin_bit_cast(u32, h);
}
static __device__ __forceinline__ float2 unpack16(u32 u) {
    __half2 h = __builtin_bit_cast(__half2, u);
    return __half22float2(h);                      // .x = low half
}

// W f32 (levels 6..15) -> packed fp16 pairs, one u32 per table entry
__global__ __launch_bounds__(256)
void convert_w(const float* __restrict__ W, u32* __restrict__ Wh, int np4)
{
    int i = blockIdx.x * blockDim.x + threadIdx.x;
    if (i >= np4) return;
    const f32x4* src = reinterpret_cast<const f32x4*>(W) + (size_t)i * 2;
    f32x4 A = __builtin_nontemporal_load(src);
    f32x4 B = __builtin_nontemporal_load(src + 1);
    u32x4 o = { packf2(A.x, A.y), packf2(A.z, A.w),
                packf2(B.x, B.y), packf2(B.z, B.w) };
    __builtin_nontemporal_store(o, reinterpret_cast<u32x4*>(Wh) + i);
}

// unpaired dense grid G[iz][iy][ix] (stride D), from f32 W, bit-identical pack
__global__ __launch_bounds__(256)
void build_unpaired(const float* __restrict__ Wlf, u32* __restrict__ Gu, int D, int P)
{
    int v = blockIdx.x * blockDim.x + threadIdx.x;
    if (v >= P) return;
    int ix = v % D;
    int rest = v / D;
    int iy = rest % D;
    int iz = rest / D;
    u32 h = (((u32)iy * PR1) ^ ((u32)iz * PR2) ^ (u32)ix) & TMASK;
    float2 f = *reinterpret_cast<const float2*>(Wlf + (size_t)h * 2u);
    Gu[v] = packf2(f.x, f.y);
}

// x-pair-duplicated grid Gp[(iz*D+iy)*(D-1)+ix] = (pack(W[h(ix)]), pack(W[h(ix+1)]))
__global__ __launch_bounds__(256)
void build_dense(const float* __restrict__ Wlf, u32x2* __restrict__ Gpl, int D, int P)
{
    int v = blockIdx.x * blockDim.x + threadIdx.x;
    if (v >= P) return;
    int Dx = D - 1;
    int ix = v % Dx;
    int rest = v / Dx;
    int iy = rest % D;
    int iz = rest / D;
    u32 e = ((u32)iy * PR1) ^ ((u32)iz * PR2);
    u32 h0 = (e ^ (u32)ix) & TMASK;
    u32 h1 = (e ^ (u32)(ix + 1)) & TMASK;
    float2 f0 = *reinterpret_cast<const float2*>(Wlf + (size_t)h0 * 2u);
    float2 f1 = *reinterpret_cast<const float2*>(Wlf + (size_t)h1 * 2u);
    u32x2 o = { packf2(f0.x, f0.y), packf2(f1.x, f1.y) };
    Gpl[v] = o;
}

// shared trilinear body for LDS-grid kernels
template<int D>
static __device__ __forceinline__ u32 lds_interp(const u32* g, float ux, float uy, float uz)
{
    int ix = (int)ux, iy = (int)uy, iz = (int)uz;
    float dx = ux - (float)ix, dy = uy - (float)iy, dz = uz - (float)iz;
    int b = (iz * D + iy) * D + ix;
    u32 c0 = g[b],             c1 = g[b + 1];
    u32 c2 = g[b + D],         c3 = g[b + D + 1];
    u32 c4 = g[b + D * D],     c5 = g[b + D * D + 1];
    u32 c6 = g[b + D * D + D], c7 = g[b + D * D + D + 1];
    float wxl = 1.f - dx, wxh = dx;
    float wyl = 1.f - dy, wyh = dy;
    float wzl = 1.f - dz, wzh = dz;
    float ax = 0.f, ay = 0.f;
    float2 f;
    f = unpack16(c0); { float w = (wxl * wyl) * wzl; ax = fmaf(f.x, w, ax); ay = fmaf(f.y, w, ay); }
    f = unpack16(c1); { float w = (wxh * wyl) * wzl; ax = fmaf(f.x, w, ax); ay = fmaf(f.y, w, ay); }
    f = unpack16(c2); { float w = (wxl * wyh) * wzl; ax = fmaf(f.x, w, ax); ay = fmaf(f.y, w, ay); }
    f = unpack16(c3); { float w = (wxh * wyh) * wzl; ax = fmaf(f.x, w, ax); ay = fmaf(f.y, w, ay); }
    f = unpack16(c4); { float w = (wxl * wyl) * wzh; ax = fmaf(f.x, w, ax); ay = fmaf(f.y, w, ay); }
    f = unpack16(c5); { float w = (wxh * wyl) * wzh; ax = fmaf(f.x, w, ax); ay = fmaf(f.y, w, ay); }
    f = unpack16(c6); { float w = (wxl * wyh) * wzh; ax = fmaf(f.x, w, ax); ay = fmaf(f.y, w, ay); }
    f = unpack16(c7); { float w = (wxh * wyh) * wzh; ax = fmaf(f.x, w, ax); ay = fmaf(f.y, w, ay); }
    return packf2(ax, ay);
}

// ---- static-LDS level kernels (levels 0,1): zero L2 gather slots ----
template<int D>
__global__ __launch_bounds__(256)
void lds_level(const float* __restrict__ x, const u32* __restrict__ Gu,
               u32* __restrict__ scl, float scale, int N)
{
    __shared__ u32 g[D * D * D];
    for (int i = threadIdx.x; i < D * D * D; i += 256) g[i] = Gu[i];
    __syncthreads();

    int base = blockIdx.x * (256 * NPTL);
    #pragma unroll 4
    for (int i = 0; i < NPTL; ++i) {
        int n = base + i * 256 + (int)threadIdx.x;
        if (n < N) {
            float px = __builtin_nontemporal_load(&x[(size_t)n * 3 + 0]);
            float py = __builtin_nontemporal_load(&x[(size_t)n * 3 + 1]);
            float pz = __builtin_nontemporal_load(&x[(size_t)n * 3 + 2]);
            __builtin_nontemporal_store(
                lds_interp<D>(g, px * scale, py * scale, pz * scale), scl + n);
        }
    }
}

// ---- dynamic-LDS level kernel (level 2: 31^3 u32 = 119KB > 64KB static) ----
template<int D>
__global__ __launch_bounds__(512)
void lds_level_dyn(const float* __restrict__ x, const u32* __restrict__ Gu,
                   u32* __restrict__ scl, float scale, int N)
{
    extern __shared__ u32 g[];
    for (int i = threadIdx.x; i < D * D * D; i += 512) g[i] = Gu[i];
    __syncthreads();

    int base = blockIdx.x * (512 * NPTL2);
    #pragma unroll 4
    for (int i = 0; i < NPTL2; ++i) {
        int n = base + i * 512 + (int)threadIdx.x;
        if (n < N) {
            float px = __builtin_nontemporal_load(&x[(size_t)n * 3 + 0]);
            float py = __builtin_nontemporal_load(&x[(size_t)n * 3 + 1]);
            float pz = __builtin_nontemporal_load(&x[(size_t)n * 3 + 2]);
            __builtin_nontemporal_store(
                lds_interp<D>(g, px * scale, py * scale, pz * scale), scl + n);
        }
    }
}

// ---- fused-kernel per-level bodies (round-9 strided batching, measured best) ----

// L2-dense: exactly 4 aligned 8B gathers per point
template<int D>
static __device__ __forceinline__ void dense_body(
    const float* __restrict__ x, const u32x2* __restrict__ Gp,
    u32* __restrict__ scl, float scale, int N, int TOT, int t)
{
    constexpr int Dx = D - 1;
    constexpr int zstep = D * Dx;

    int nn[NPT];
    float dx[NPT], dy[NPT], dz[NPT];
    int base[NPT];
    u32x2 P0[NPT], P1[NPT], P2[NPT], P3[NPT];

    #pragma unroll
    for (int i = 0; i < NPT; ++i) {
        int n = t + i * TOT;
        if (n > N - 1) n = N - 1;          // duplicate write of same value: benign
        nn[i] = n;
        float px = __builtin_nontemporal_load(&x[(size_t)n * 3 + 0]);
        float py = __builtin_nontemporal_load(&x[(size_t)n * 3 + 1]);
        float pz = __builtin_nontemporal_load(&x[(size_t)n * 3 + 2]);
        float ux = px * scale, uy = py * scale, uz = pz * scale;
        int ix = (int)ux, iy = (int)uy, iz = (int)uz;   // trunc == floor (x>=0)
        dx[i] = ux - (float)ix;
        dy[i] = uy - (float)iy;
        dz[i] = uz - (float)iz;
        base[i] = (iz * D + iy) * Dx + ix;
    }

    #pragma unroll
    for (int i = 0; i < NPT; ++i) {
        int b = base[i];
        P0[i] = Gp[b];                 // corners v0,v1 (iy, iz)
        P1[i] = Gp[b + Dx];            // v2,v3 (iy+1, iz)
        P2[i] = Gp[b + zstep];         // v4,v5 (iy, iz+1)
        P3[i] = Gp[b + zstep + Dx];    // v6,v7 (iy+1, iz+1)
    }

    #pragma unroll
    for (int i = 0; i < NPT; ++i) {
        float ax = 0.f, ay = 0.f;
        float wxl = 1.f - dx[i], wxh = dx[i];
        float wyl = 1.f - dy[i], wyh = dy[i];
        float wzl = 1.f - dz[i], wzh = dz[i];
        {
            float2 f0 = unpack16(P0[i].x), f1 = unpack16(P0[i].y);
            float w0 = (wxl * wyl) * wzl, w1 = (wxh * wyl) * wzl;
            ax = fmaf(f0.x, w0, ax); ay = fmaf(f0.y, w0, ay);
            ax = fmaf(f1.x, w1, ax); ay = fmaf(f1.y, w1, ay);
        }
        {
            float2 f0 = unpack16(P1[i].x), f1 = unpack16(P1[i].y);
            float w0 = (wxl * wyh) * wzl, w1 = (wxh * wyh) * wzl;
            ax = fmaf(f0.x, w0, ax); ay = fmaf(f0.y, w0, ay);
            ax = fmaf(f1.x, w1, ax); ay = fmaf(f1.y, w1, ay);
        }
        {
            float2 f0 = unpack16(P2[i].x), f1 = unpack16(P2[i].y);
            float w0 = (wxl * wyl) * wzh, w1 = (wxh * wyl) * wzh;
            ax = fmaf(f0.x, w0, ax); ay = fmaf(f0.y, w0, ay);
            ax = fmaf(f1.x, w1, ax); ay = fmaf(f1.y, w1, ay);
        }
        {
            float2 f0 = unpack16(P3[i].x), f1 = unpack16(P3[i].y);
            float w0 = (wxl * wyh) * wzh, w1 = (wxh * wyh) * wzh;
            ax = fmaf(f0.x, w0, ax); ay = fmaf(f0.y, w0, ay);
            ax = fmaf(f1.x, w1, ax); ay = fmaf(f1.y, w1, ay);
        }
        __builtin_nontemporal_store(packf2(ax, ay), scl + nn[i]);
    }
}

// hash: even-ix u32x2 pairing, avg 6 8B-requests/pt
static __device__ __forceinline__ void hash_body(
    const float* __restrict__ x, const u32* __restrict__ Wl,
    u32* __restrict__ scl, float scale, int N, int TOT, int t)
{
    int nn[NPT];
    float dx[NPT], dy[NPT], dz[NPT];
    u32 a0[NPT], a1[NPT], a2[NPT];
    u32 fv[NPT][8];

    #pragma unroll
    for (int i = 0; i < NPT; ++i) {
        int n = t + i * TOT;
        if (n > N - 1) n = N - 1;
        nn[i] = n;
        float px = __builtin_nontemporal_load(&x[(size_t)n * 3 + 0]);
        float py = __builtin_nontemporal_load(&x[(size_t)n * 3 + 1]);
        float pz = __builtin_nontemporal_load(&x[(size_t)n * 3 + 2]);
        float ux = px * scale, uy = py * scale, uz = pz * scale;
        int ix = (int)ux, iy = (int)uy, iz = (int)uz;
        dx[i] = ux - (float)ix;
        dy[i] = uy - (float)iy;
        dz[i] = uz - (float)iz;
        a0[i] = (unsigned)ix;
        a1[i] = (unsigned)iy * PR1;
        a2[i] = (unsigned)iz * PR2;
    }

    #pragma unroll
    for (int i = 0; i < NPT; ++i) {
        u32 b0 = a0[i] + 1u, b1 = a1[i] + PR1, b2 = a2[i] + PR2;
        u32 E[4] = { a1[i] ^ a2[i], b1 ^ a2[i], a1[i] ^ b2, b1 ^ b2 };
        if ((a0[i] & 1u) == 0u) {
            #pragma unroll
            for (int j = 0; j < 4; ++j) {
                u32 hl = (E[j] ^ a0[i]) & TMASK;       // h_hi = hl ^ 1
                u32x2 p = *reinterpret_cast<const u32x2*>(Wl + (hl & ~1u));
                u32 lo = (hl & 1u) ? p.y : p.x;
                u32 hi = (hl & 1u) ? p.x : p.y;
                fv[i][2 * j + 0] = lo;
                fv[i][2 * j + 1] = hi;
            }
        } else {
            #pragma unroll
            for (int j = 0; j < 4; ++j) {
                u32 hl = (E[j] ^ a0[i]) & TMASK;
                u32 hh = (E[j] ^ b0) & TMASK;
                fv[i][2 * j + 0] = Wl[hl];
                fv[i][2 * j + 1] = Wl[hh];
            }
        }
    }

    #pragma unroll
    for (int i = 0; i < NPT; ++i) {
        float ax = 0.f, ay = 0.f;
        #pragma unroll
        for (int v = 0; v < 8; ++v) {
            float wx = (v & 1) ? dx[i] : 1.f - dx[i];
            float wy = (v & 2) ? dy[i] : 1.f - dy[i];
            float wz = (v & 4) ? dz[i] : 1.f - dz[i];
            float w = (wx * wy) * wz;
            float2 f = unpack16(fv[i][v]);
            ax = fmaf(f.x, w, ax);
            ay = fmaf(f.y, w, ay);
        }
        __builtin_nontemporal_store(packf2(ax, ay), scl + nn[i]);
    }
}

// Fused kernel for levels lstart..15 (level-major block order keeps L2 locality)
__global__ __launch_bounds__(256)
void fused_levels(const float* __restrict__ x, const u32* __restrict__ Wh,
                  const u32x2* __restrict__ Gp, u32* __restrict__ scratch,
                  ScaleArgs sc, int N, int TOT, int BPL, int lstart)
{
    int li = blockIdx.x / BPL;
    int lvl = li + lstart;
    int t = (blockIdx.x - li * BPL) * blockDim.x + threadIdx.x;
    if (t >= TOT) return;
    float scale = sc.s[lvl];
    u32* scl = scratch + (size_t)lvl * (size_t)N;

    switch (lvl) {   // block-uniform
        case 2: dense_body<DD2>(x, Gp + GO2, scl, scale, N, TOT, t); break;
        case 3: dense_body<DD3>(x, Gp + GO3, scl, scale, N, TOT, t); break;
        case 4: dense_body<DD4>(x, Gp + GO4, scl, scale, N, TOT, t); break;
        case 5: dense_body<DD5>(x, Gp + GO5, scl, scale, N, TOT, t); break;
        default:
            hash_body(x, Wh + (size_t)(lvl - 6) * TBLN, scl, scale, N, TOT, t);
            break;
    }
}

// LDS-staged transpose: load 256 pts x 16 levels coalesced, emit 1KB-contiguous
// full-line NT stores per wave.
__global__ __launch_bounds__(256)
void transpose_kernel(const u32* __restrict__ sc, float* __restrict__ out, int N)
{
    __shared__ u32 lds[16][257];
    int P0 = blockIdx.x * 256;
    int t = threadIdx.x;
    #pragma unroll
    for (int l = 0; l < NLEV; ++l) {
        int n = P0 + t;
        if (n < N) lds[l][t] = __builtin_nontemporal_load(sc + (size_t)l * N + n);
    }
    __syncthreads();
    int w = t >> 6, l6 = t & 63;
    #pragma unroll
    for (int k = 0; k < 8; ++k) {
        int p = w * 64 + k * 8 + (l6 >> 3);
        int c = l6 & 7;                       // chunk covers levels 2c, 2c+1
        if (P0 + p < N) {
            float2 f0 = unpack16(lds[2 * c][p]);
            float2 f1 = unpack16(lds[2 * c + 1][p]);
            f32x4 v = { f0.x, f0.y, f1.x, f1.y };
            __builtin_nontemporal_store(v,
                reinterpret_cast<f32x4*>(out + (size_t)(P0 + p) * 32u + (size_t)c * 4u));
        }
    }
}

// ---------------- fallback (round-1 kernel, known-good, f32 exact) ----------
__global__ __launch_bounds__(256)
void hashenc_fallback(const float* __restrict__ x, const float* __restrict__ W,
                      float* __restrict__ out, ScaleArgs sc, int N)
{
    int n = blockIdx.x * blockDim.x + threadIdx.x;
    if (n >= N) return;
    float px = x[(size_t)n * 3 + 0];
    float py = x[(size_t)n * 3 + 1];
    float pz = x[(size_t)n * 3 + 2];
    float acc[2 * NLEV];
    #pragma unroll
    for (int l = 0; l < NLEV; ++l) {
        float s = sc.s[l];
        float ux = px * s, uy = py * s, uz = pz * s;
        int ix = (int)ux, iy = (int)uy, iz = (int)uz;
        float dx = ux - (float)ix, dy = uy - (float)iy, dz = uz - (float)iz;
        unsigned a0 = (unsigned)ix;
        unsigned a1 = (unsigned)iy * PR1;
        unsigned a2 = (unsigned)iz * PR2;
        unsigned b0 = a0 + 1u, b1 = a1 + PR1, b2 = a2 + PR2;
        const float* Wl = W + (size_t)l * TBLN * 2u;
        float ax = 0.f, ay = 0.f;
        #pragma unroll
        for (int v = 0; v < 8; ++v) {
            unsigned h = ((v & 1) ? b0 : a0) ^ ((v & 2) ? b1 : a1) ^ ((v & 4) ? b2 : a2);
            h &= TMASK;
            float wx = (v & 1) ? dx : 1.f - dx;
            float wy = (v & 2) ? dy : 1.f - dy;
            float wz = (v & 4) ? dz : 1.f - dz;
            float w = (wx * wy) * wz;
            const float2 fvv = *reinterpret_cast<const float2*>(Wl + (size_t)h * 2u);
            ax = fmaf(fvv.x, w, ax);
            ay = fmaf(fvv.y, w, ay);
        }
        acc[2 * l + 0] = ax;
        acc[2 * l + 1] = ay;
    }
    float4* o = reinterpret_cast<float4*>(out + (size_t)n * (2 * NLEV));
    #pragma unroll
    for (int j = 0; j < 8; ++j)
        o[j] = make_float4(acc[4 * j + 0], acc[4 * j + 1], acc[4 * j + 2], acc[4 * j + 3]);
}

extern "C" void kernel_launch(void* const* d_in, const int* in_sizes, int n_in,
                              void* d_out, int out_size, void* d_ws, size_t ws_size,
                              hipStream_t stream) {
    const float* x = (const float*)d_in[0];
    const float* W = (const float*)d_in[1];
    float* out = (float*)d_out;
    int N = in_sizes[0] / 3;

    // numpy-exact scales
    ScaleArgs sc;
    double b = exp((log(2048.0) - log(16.0)) / 16.0);
    for (int l = 0; l < NLEV; ++l) {
        double p;
        switch (l) {
            case 0: p = 1.0; break;
            case 1: p = b;   break;
            case 2: p = b * b; break;
            default: p = pow(b, (double)l); break;
        }
        sc.s[l] = (float)(16.0 * p);
    }

    // workspace layout (u32 units): [Wh 10 tables][Gp paired 2..5][Gu 0,1,2][scratch]
    size_t wh_u32 = (size_t)(NLEV - 6) * TBLN;        // 21.0 MB
    size_t gp_u32 = (size_t)GPTOT * 2u;               // 5.4 MB
    size_t gu_u32 = (size_t)GUTOT;                    // 191 KB
    size_t scr_u32 = (size_t)NLEV * (size_t)N;        // 128 MB
    size_t need = (wh_u32 + gp_u32 + gu_u32 + scr_u32) * sizeof(u32);  // ~154.6 MB

    if (ws_size >= need) {
        u32* Wh = (u32*)d_ws;
        u32x2* Gp = reinterpret_cast<u32x2*>(Wh + wh_u32);
        u32* Gu = Wh + wh_u32 + gp_u32;
        u32* scratch = Gu + gu_u32;

        // level-2 dynamic LDS: 31^3 u32 = 119164 B (>64KB static limit).
        // Host-side attribute set; deterministic per-process result.
        size_t l2_lds_bytes = (size_t)DU2 * DU2 * DU2 * sizeof(u32);
        bool lvl2_lds = (hipFuncSetAttribute(
                             (const void*)&lds_level_dyn<DU2>,
                             hipFuncAttributeMaxDynamicSharedMemorySize,
                             (int)l2_lds_bytes) == hipSuccess);

        // fp16 tables for hash levels 6..15
        int np4 = (int)(wh_u32 / 4);
        hipLaunchKernelGGL(convert_w, dim3((np4 + 255) / 256), dim3(256), 0, stream,
                           W + (size_t)6 * TBLN * 2u, Wh, np4);

        // unpaired LDS grids for levels 0,1,2
        {
            int P0c = DU0 * DU0 * DU0;
            hipLaunchKernelGGL(build_unpaired, dim3((P0c + 255) / 256), dim3(256), 0, stream,
                               W + 0, Gu + GU0, DU0, P0c);
            int P1c = DU1 * DU1 * DU1;
            hipLaunchKernelGGL(build_unpaired, dim3((P1c + 255) / 256), dim3(256), 0, stream,
                               W + (size_t)1 * TBLN * 2u, Gu + GU1, DU1, P1c);
            int P2c = DU2 * DU2 * DU2;
            hipLaunchKernelGGL(build_unpaired, dim3((P2c + 255) / 256), dim3(256), 0, stream,
                               W + (size_t)2 * TBLN * 2u, Gu + GU2, DU2, P2c);
        }

        // paired grids for levels 2..5 (level 2 used only in non-LDS fallback)
        const int Dl[4] = { DD2, DD3, DD4, DD5 };
        const int Ol[4] = { GO2, GO3, GO4, GO5 };
        for (int i = 0; i < 4; ++i) {
            int l = 2 + i;
            int P = (Dl[i] - 1) * Dl[i] * Dl[i];
            hipLaunchKernelGGL(build_dense, dim3((P + 255) / 256), dim3(256), 0, stream,
                               W + (size_t)l * TBLN * 2u, Gp + Ol[i], Dl[i], P);
        }

        // levels 0,1 via static LDS grids (zero L2 gather slots)
        {
            int blocks = (N + 256 * NPTL - 1) / (256 * NPTL);
            hipLaunchKernelGGL(lds_level<DU0>, dim3(blocks), dim3(256), 0, stream,
                               x, Gu + GU0, scratch + 0, sc.s[0], N);
            hipLaunchKernelGGL(lds_level<DU1>, dim3(blocks), dim3(256), 0, stream,
                               x, Gu + GU1, scratch + (size_t)N, sc.s[1], N);
        }

        // level 2 via dynamic LDS if available
        if (lvl2_lds) {
            int blocks = (N + 512 * NPTL2 - 1) / (512 * NPTL2);
            hipLaunchKernelGGL(lds_level_dyn<DU2>, dim3(blocks), dim3(512),
                               l2_lds_bytes, stream,
                               x, Gu + GU2, scratch + (size_t)2 * N, sc.s[2], N);
        }

        // remaining levels fused (level-major, strided batching)
        int lstart = lvl2_lds ? 3 : 2;
        int TOT = (N + NPT - 1) / NPT;
        int BPL = (TOT + 255) / 256;
        hipLaunchKernelGGL(fused_levels, dim3((16 - lstart) * BPL), dim3(256), 0, stream,
                           x, Wh, Gp, scratch, sc, N, TOT, BPL, lstart);

        int gt = (N + 255) / 256;
        hipLaunchKernelGGL(transpose_kernel, dim3(gt), dim3(256), 0, stream,
                           scratch, out, N);
    } else {
        int grid = (N + 255) / 256;
        hipLaunchKernelGGL(hashenc_fallback, dim3(grid), dim3(256), 0, stream,
                           x, W, out, sc, N);
    }
}

// Round 12
// 607.017 us; speedup vs baseline: 1.0564x; 1.0333x over previous
//
#include <hip/hip_runtime.h>
#include <hip/hip_fp16.h>
#include <math.h>

#define NLEV 16
#define TBLN (1u << 19)
#define TMASK (TBLN - 1u)
#define NPT 4             // points per thread in fused level kernel (strided)
#define NPTL 16           // points per thread in static LDS level kernels
#define NPTL2 8           // points per thread in dynamic LDS level-2 kernel
#define PR1 2654435761u
#define PR2 805459861u

typedef float f32x4 __attribute__((ext_vector_type(4)));
typedef unsigned int u32;
typedef unsigned int u32x2 __attribute__((ext_vector_type(2)));
typedef unsigned int u32x4 __attribute__((ext_vector_type(4)));

struct ScaleArgs { float s[NLEV]; };

// ---- compile-time geometry (scales fixed: 16,21.7,29.4,39.8,53.9,72.9,...) ----
// LDS levels 0,1,2: unpaired u32 grids D^3 (level 2 via dynamic LDS, 119KB)
#define DU0 18
#define DU1 23
#define DU2 31
#define GU0 0
#define GU1 5832            /* 18^3 */
#define GU2 17999           /* + 23^3 */
#define GUTOT 47790         /* + 31^3 */
// x-pair 8B grids: level 2 (fallback) and level 5
#define DD2 31
#define DD5 75
#define PO2 0
#define PO5 28830           /* 30*31*31 */
#define GPTOT2 445080       /* + 74*75*75 */
// xy-quad 16B grids: levels 3,4  (D*(D-1)^2 quads)
#define DD3 41
#define DD4 55
#define QO3 0
#define QO4 65600           /* 40*40*41 */
#define GQTOT 225980        /* + 54*54*55 */

static __device__ __forceinline__ u32 packf2(float a, float b) {
    __half2 h = __floats2half2_rn(a, b);          // low16 = a, high16 = b
    return __builtin_bit_cast(u32, h);
}
static __device__ __forceinline__ float2 unpack16(u32 u) {
    __half2 h = __builtin_bit_cast(__half2, u);
    return __half22float2(h);                      // .x = low half
}
// runtime 4-way select from u32x4 without memory (cndmask chain, no scratch)
static __device__ __forceinline__ u32 sel4(u32x4 P, u32 idx) {
    u32 s0 = (idx & 1u) ? P.y : P.x;
    u32 s1 = (idx & 1u) ? P.w : P.z;
    return (idx & 2u) ? s1 : s0;
}

// W f32 (levels 6..15) -> packed fp16 pairs, one u32 per table entry
__global__ __launch_bounds__(256)
void convert_w(const float* __restrict__ W, u32* __restrict__ Wh, int np4)
{
    int i = blockIdx.x * blockDim.x + threadIdx.x;
    if (i >= np4) return;
    const f32x4* src = reinterpret_cast<const f32x4*>(W) + (size_t)i * 2;
    f32x4 A = __builtin_nontemporal_load(src);
    f32x4 B = __builtin_nontemporal_load(src + 1);
    u32x4 o = { packf2(A.x, A.y), packf2(A.z, A.w),
                packf2(B.x, B.y), packf2(B.z, B.w) };
    __builtin_nontemporal_store(o, reinterpret_cast<u32x4*>(Wh) + i);
}

// unpaired dense grid G[iz][iy][ix] (stride D), from f32 W, bit-identical pack
__global__ __launch_bounds__(256)
void build_unpaired(const float* __restrict__ Wlf, u32* __restrict__ Gu, int D, int P)
{
    int v = blockIdx.x * blockDim.x + threadIdx.x;
    if (v >= P) return;
    int ix = v % D;
    int rest = v / D;
    int iy = rest % D;
    int iz = rest / D;
    u32 h = (((u32)iy * PR1) ^ ((u32)iz * PR2) ^ (u32)ix) & TMASK;
    float2 f = *reinterpret_cast<const float2*>(Wlf + (size_t)h * 2u);
    Gu[v] = packf2(f.x, f.y);
}

// x-pair grid Gp[(iz*D+iy)*(D-1)+ix] = (pack(W[h(ix)]), pack(W[h(ix+1)]))
__global__ __launch_bounds__(256)
void build_dense(const float* __restrict__ Wlf, u32x2* __restrict__ Gpl, int D, int P)
{
    int v = blockIdx.x * blockDim.x + threadIdx.x;
    if (v >= P) return;
    int Dx = D - 1;
    int ix = v % Dx;
    int rest = v / Dx;
    int iy = rest % D;
    int iz = rest / D;
    u32 e = ((u32)iy * PR1) ^ ((u32)iz * PR2);
    u32 h0 = (e ^ (u32)ix) & TMASK;
    u32 h1 = (e ^ (u32)(ix + 1)) & TMASK;
    float2 f0 = *reinterpret_cast<const float2*>(Wlf + (size_t)h0 * 2u);
    float2 f1 = *reinterpret_cast<const float2*>(Wlf + (size_t)h1 * 2u);
    u32x2 o = { packf2(f0.x, f0.y), packf2(f1.x, f1.y) };
    Gpl[v] = o;
}

// xy-quad grid Gq[(iz*(D-1)+iy)*(D-1)+ix] = corners {(ix,iy),(ix+1,iy),(ix,iy+1),(ix+1,iy+1)}
__global__ __launch_bounds__(256)
void build_dense16(const float* __restrict__ Wlf, u32x4* __restrict__ Gql, int D, int P)
{
    int v = blockIdx.x * blockDim.x + threadIdx.x;
    if (v >= P) return;
    int Dx = D - 1;
    int ix = v % Dx;
    int rest = v / Dx;
    int iy = rest % Dx;
    int iz = rest / Dx;
    u32 ey0 = ((u32)iy * PR1) ^ ((u32)iz * PR2);
    u32 ey1 = ((u32)(iy + 1) * PR1) ^ ((u32)iz * PR2);
    u32 h00 = (ey0 ^ (u32)ix) & TMASK;
    u32 h10 = (ey0 ^ (u32)(ix + 1)) & TMASK;
    u32 h01 = (ey1 ^ (u32)ix) & TMASK;
    u32 h11 = (ey1 ^ (u32)(ix + 1)) & TMASK;
    float2 f00 = *reinterpret_cast<const float2*>(Wlf + (size_t)h00 * 2u);
    float2 f10 = *reinterpret_cast<const float2*>(Wlf + (size_t)h10 * 2u);
    float2 f01 = *reinterpret_cast<const float2*>(Wlf + (size_t)h01 * 2u);
    float2 f11 = *reinterpret_cast<const float2*>(Wlf + (size_t)h11 * 2u);
    u32x4 o = { packf2(f00.x, f00.y), packf2(f10.x, f10.y),
                packf2(f01.x, f01.y), packf2(f11.x, f11.y) };
    Gql[v] = o;
}

// shared trilinear body for LDS-grid kernels
template<int D>
static __device__ __forceinline__ u32 lds_interp(const u32* g, float ux, float uy, float uz)
{
    int ix = (int)ux, iy = (int)uy, iz = (int)uz;
    float dx = ux - (float)ix, dy = uy - (float)iy, dz = uz - (float)iz;
    int b = (iz * D + iy) * D + ix;
    u32 c0 = g[b],             c1 = g[b + 1];
    u32 c2 = g[b + D],         c3 = g[b + D + 1];
    u32 c4 = g[b + D * D],     c5 = g[b + D * D + 1];
    u32 c6 = g[b + D * D + D], c7 = g[b + D * D + D + 1];
    float wxl = 1.f - dx, wxh = dx;
    float wyl = 1.f - dy, wyh = dy;
    float wzl = 1.f - dz, wzh = dz;
    float ax = 0.f, ay = 0.f;
    float2 f;
    f = unpack16(c0); { float w = (wxl * wyl) * wzl; ax = fmaf(f.x, w, ax); ay = fmaf(f.y, w, ay); }
    f = unpack16(c1); { float w = (wxh * wyl) * wzl; ax = fmaf(f.x, w, ax); ay = fmaf(f.y, w, ay); }
    f = unpack16(c2); { float w = (wxl * wyh) * wzl; ax = fmaf(f.x, w, ax); ay = fmaf(f.y, w, ay); }
    f = unpack16(c3); { float w = (wxh * wyh) * wzl; ax = fmaf(f.x, w, ax); ay = fmaf(f.y, w, ay); }
    f = unpack16(c4); { float w = (wxl * wyl) * wzh; ax = fmaf(f.x, w, ax); ay = fmaf(f.y, w, ay); }
    f = unpack16(c5); { float w = (wxh * wyl) * wzh; ax = fmaf(f.x, w, ax); ay = fmaf(f.y, w, ay); }
    f = unpack16(c6); { float w = (wxl * wyh) * wzh; ax = fmaf(f.x, w, ax); ay = fmaf(f.y, w, ay); }
    f = unpack16(c7); { float w = (wxh * wyh) * wzh; ax = fmaf(f.x, w, ax); ay = fmaf(f.y, w, ay); }
    return packf2(ax, ay);
}

// ---- static-LDS level kernels (levels 0,1): zero L2 gather slots ----
template<int D>
__global__ __launch_bounds__(256)
void lds_level(const float* __restrict__ x, const u32* __restrict__ Gu,
               u32* __restrict__ scl, float scale, int N)
{
    __shared__ u32 g[D * D * D];
    for (int i = threadIdx.x; i < D * D * D; i += 256) g[i] = Gu[i];
    __syncthreads();

    int base = blockIdx.x * (256 * NPTL);
    #pragma unroll 4
    for (int i = 0; i < NPTL; ++i) {
        int n = base + i * 256 + (int)threadIdx.x;
        if (n < N) {
            float px = __builtin_nontemporal_load(&x[(size_t)n * 3 + 0]);
            float py = __builtin_nontemporal_load(&x[(size_t)n * 3 + 1]);
            float pz = __builtin_nontemporal_load(&x[(size_t)n * 3 + 2]);
            __builtin_nontemporal_store(
                lds_interp<D>(g, px * scale, py * scale, pz * scale), scl + n);
        }
    }
}

// ---- dynamic-LDS level kernel (level 2: 31^3 u32 = 119KB > 64KB static) ----
template<int D>
__global__ __launch_bounds__(512)
void lds_level_dyn(const float* __restrict__ x, const u32* __restrict__ Gu,
                   u32* __restrict__ scl, float scale, int N)
{
    extern __shared__ u32 g[];
    for (int i = threadIdx.x; i < D * D * D; i += 512) g[i] = Gu[i];
    __syncthreads();

    int base = blockIdx.x * (512 * NPTL2);
    #pragma unroll 4
    for (int i = 0; i < NPTL2; ++i) {
        int n = base + i * 512 + (int)threadIdx.x;
        if (n < N) {
            float px = __builtin_nontemporal_load(&x[(size_t)n * 3 + 0]);
            float py = __builtin_nontemporal_load(&x[(size_t)n * 3 + 1]);
            float pz = __builtin_nontemporal_load(&x[(size_t)n * 3 + 2]);
            __builtin_nontemporal_store(
                lds_interp<D>(g, px * scale, py * scale, pz * scale), scl + n);
        }
    }
}

// ---- fused-kernel per-level bodies (strided batching, measured best) ----

// x-pair 8B dense: exactly 4 aligned 8B gathers per point
template<int D>
static __device__ __forceinline__ void dense_body(
    const float* __restrict__ x, const u32x2* __restrict__ Gp,
    u32* __restrict__ scl, float scale, int N, int TOT, int t)
{
    constexpr int Dx = D - 1;
    constexpr int zstep = D * Dx;

    int nn[NPT];
    float dx[NPT], dy[NPT], dz[NPT];
    int base[NPT];
    u32x2 P0[NPT], P1[NPT], P2[NPT], P3[NPT];

    #pragma unroll
    for (int i = 0; i < NPT; ++i) {
        int n = t + i * TOT;
        if (n > N - 1) n = N - 1;          // duplicate write of same value: benign
        nn[i] = n;
        float px = __builtin_nontemporal_load(&x[(size_t)n * 3 + 0]);
        float py = __builtin_nontemporal_load(&x[(size_t)n * 3 + 1]);
        float pz = __builtin_nontemporal_load(&x[(size_t)n * 3 + 2]);
        float ux = px * scale, uy = py * scale, uz = pz * scale;
        int ix = (int)ux, iy = (int)uy, iz = (int)uz;   // trunc == floor (x>=0)
        dx[i] = ux - (float)ix;
        dy[i] = uy - (float)iy;
        dz[i] = uz - (float)iz;
        base[i] = (iz * D + iy) * Dx + ix;
    }

    #pragma unroll
    for (int i = 0; i < NPT; ++i) {
        int b = base[i];
        P0[i] = Gp[b];                 // corners v0,v1 (iy, iz)
        P1[i] = Gp[b + Dx];            // v2,v3 (iy+1, iz)
        P2[i] = Gp[b + zstep];         // v4,v5 (iy, iz+1)
        P3[i] = Gp[b + zstep + Dx];    // v6,v7 (iy+1, iz+1)
    }

    #pragma unroll
    for (int i = 0; i < NPT; ++i) {
        float ax = 0.f, ay = 0.f;
        float wxl = 1.f - dx[i], wxh = dx[i];
        float wyl = 1.f - dy[i], wyh = dy[i];
        float wzl = 1.f - dz[i], wzh = dz[i];
        {
            float2 f0 = unpack16(P0[i].x), f1 = unpack16(P0[i].y);
            float w0 = (wxl * wyl) * wzl, w1 = (wxh * wyl) * wzl;
            ax = fmaf(f0.x, w0, ax); ay = fmaf(f0.y, w0, ay);
            ax = fmaf(f1.x, w1, ax); ay = fmaf(f1.y, w1, ay);
        }
        {
            float2 f0 = unpack16(P1[i].x), f1 = unpack16(P1[i].y);
            float w0 = (wxl * wyh) * wzl, w1 = (wxh * wyh) * wzl;
            ax = fmaf(f0.x, w0, ax); ay = fmaf(f0.y, w0, ay);
            ax = fmaf(f1.x, w1, ax); ay = fmaf(f1.y, w1, ay);
        }
        {
            float2 f0 = unpack16(P2[i].x), f1 = unpack16(P2[i].y);
            float w0 = (wxl * wyl) * wzh, w1 = (wxh * wyl) * wzh;
            ax = fmaf(f0.x, w0, ax); ay = fmaf(f0.y, w0, ay);
            ax = fmaf(f1.x, w1, ax); ay = fmaf(f1.y, w1, ay);
        }
        {
            float2 f0 = unpack16(P3[i].x), f1 = unpack16(P3[i].y);
            float w0 = (wxl * wyh) * wzh, w1 = (wxh * wyh) * wzh;
            ax = fmaf(f0.x, w0, ax); ay = fmaf(f0.y, w0, ay);
            ax = fmaf(f1.x, w1, ax); ay = fmaf(f1.y, w1, ay);
        }
        __builtin_nontemporal_store(packf2(ax, ay), scl + nn[i]);
    }
}

// xy-quad 16B dense (levels 3,4): exactly 2 aligned 16B gathers per point
template<int D>
static __device__ __forceinline__ void dense16_body(
    const float* __restrict__ x, const u32x4* __restrict__ Gq,
    u32* __restrict__ scl, float scale, int N, int TOT, int t)
{
    constexpr int Dx = D - 1;
    constexpr int zstep = Dx * Dx;     // quads per z-slice

    int nn[NPT];
    float dx[NPT], dy[NPT], dz[NPT];
    int base[NPT];
    u32x4 Q0[NPT], Q1[NPT];

    #pragma unroll
    for (int i = 0; i < NPT; ++i) {
        int n = t + i * TOT;
        if (n > N - 1) n = N - 1;
        nn[i] = n;
        float px = __builtin_nontemporal_load(&x[(size_t)n * 3 + 0]);
        float py = __builtin_nontemporal_load(&x[(size_t)n * 3 + 1]);
        float pz = __builtin_nontemporal_load(&x[(size_t)n * 3 + 2]);
        float ux = px * scale, uy = py * scale, uz = pz * scale;
        int ix = (int)ux, iy = (int)uy, iz = (int)uz;
        dx[i] = ux - (float)ix;
        dy[i] = uy - (float)iy;
        dz[i] = uz - (float)iz;
        base[i] = (iz * Dx + iy) * Dx + ix;
    }

    #pragma unroll
    for (int i = 0; i < NPT; ++i) {
        Q0[i] = Gq[base[i]];           // corners v0..v3 (z=iz)
        Q1[i] = Gq[base[i] + zstep];   // corners v4..v7 (z=iz+1)
    }

    #pragma unroll
    for (int i = 0; i < NPT; ++i) {
        float ax = 0.f, ay = 0.f;
        float wxl = 1.f - dx[i], wxh = dx[i];
        float wyl = 1.f - dy[i], wyh = dy[i];
        float wzl = 1.f - dz[i], wzh = dz[i];
        float2 f;
        f = unpack16(Q0[i].x); { float w = (wxl * wyl) * wzl; ax = fmaf(f.x, w, ax); ay = fmaf(f.y, w, ay); }
        f = unpack16(Q0[i].y); { float w = (wxh * wyl) * wzl; ax = fmaf(f.x, w, ax); ay = fmaf(f.y, w, ay); }
        f = unpack16(Q0[i].z); { float w = (wxl * wyh) * wzl; ax = fmaf(f.x, w, ax); ay = fmaf(f.y, w, ay); }
        f = unpack16(Q0[i].w); { float w = (wxh * wyh) * wzl; ax = fmaf(f.x, w, ax); ay = fmaf(f.y, w, ay); }
        f = unpack16(Q1[i].x); { float w = (wxl * wyl) * wzh; ax = fmaf(f.x, w, ax); ay = fmaf(f.y, w, ay); }
        f = unpack16(Q1[i].y); { float w = (wxh * wyl) * wzh; ax = fmaf(f.x, w, ax); ay = fmaf(f.y, w, ay); }
        f = unpack16(Q1[i].z); { float w = (wxl * wyh) * wzh; ax = fmaf(f.x, w, ax); ay = fmaf(f.y, w, ay); }
        f = unpack16(Q1[i].w); { float w = (wxh * wyh) * wzh; ax = fmaf(f.x, w, ax); ay = fmaf(f.y, w, ay); }
        __builtin_nontemporal_store(packf2(ax, ay), scl + nn[i]);
    }
}

// hash: 3-way pairing. even ix -> (hl,hl^1) aligned 8B (1 slot);
// ix%4==1 -> (hl,hl^3) in aligned 16B (1.42 slots); ix%4==3 -> 2 scalars.
static __device__ __forceinline__ void hash_body(
    const float* __restrict__ x, const u32* __restrict__ Wl,
    u32* __restrict__ scl, float scale, int N, int TOT, int t)
{
    int nn[NPT];
    float dx[NPT], dy[NPT], dz[NPT];
    u32 a0[NPT], a1[NPT], a2[NPT];
    u32 fv[NPT][8];

    #pragma unroll
    for (int i = 0; i < NPT; ++i) {
        int n = t + i * TOT;
        if (n > N - 1) n = N - 1;
        nn[i] = n;
        float px = __builtin_nontemporal_load(&x[(size_t)n * 3 + 0]);
        float py = __builtin_nontemporal_load(&x[(size_t)n * 3 + 1]);
        float pz = __builtin_nontemporal_load(&x[(size_t)n * 3 + 2]);
        float ux = px * scale, uy = py * scale, uz = pz * scale;
        int ix = (int)ux, iy = (int)uy, iz = (int)uz;
        dx[i] = ux - (float)ix;
        dy[i] = uy - (float)iy;
        dz[i] = uz - (float)iz;
        a0[i] = (unsigned)ix;
        a1[i] = (unsigned)iy * PR1;
        a2[i] = (unsigned)iz * PR2;
    }

    #pragma unroll
    for (int i = 0; i < NPT; ++i) {
        u32 b0 = a0[i] + 1u, b1 = a1[i] + PR1, b2 = a2[i] + PR2;
        u32 E[4] = { a1[i] ^ a2[i], b1 ^ a2[i], a1[i] ^ b2, b1 ^ b2 };
        u32 par = a0[i] & 3u;
        if ((par & 1u) == 0u) {
            // even ix: h(ix+1) = hl^1 -> aligned 8B pair
            #pragma unroll
            for (int j = 0; j < 4; ++j) {
                u32 hl = (E[j] ^ a0[i]) & TMASK;
                u32x2 p = *reinterpret_cast<const u32x2*>(Wl + (hl & ~1u));
                fv[i][2 * j + 0] = (hl & 1u) ? p.y : p.x;
                fv[i][2 * j + 1] = (hl & 1u) ? p.x : p.y;
            }
        } else if (par == 1u) {
            // ix%4==1: ix^(ix+1)=3 -> h(ix+1)=hl^3, both in aligned 16B chunk
            #pragma unroll
            for (int j = 0; j < 4; ++j) {
                u32 hl = (E[j] ^ a0[i]) & TMASK;
                u32x4 P = *reinterpret_cast<const u32x4*>(Wl + (hl & ~3u));
                u32 il = hl & 3u;
                fv[i][2 * j + 0] = sel4(P, il);
                fv[i][2 * j + 1] = sel4(P, il ^ 3u);
            }
        } else {
            // ix%4==3: carry flips >=3 bits -> 2 scalar loads per pair
            #pragma unroll
            for (int j = 0; j < 4; ++j) {
                u32 hl = (E[j] ^ a0[i]) & TMASK;
                u32 hh = (E[j] ^ b0) & TMASK;
                fv[i][2 * j + 0] = Wl[hl];
                fv[i][2 * j + 1] = Wl[hh];
            }
        }
    }

    #pragma unroll
    for (int i = 0; i < NPT; ++i) {
        float ax = 0.f, ay = 0.f;
        #pragma unroll
        for (int v = 0; v < 8; ++v) {
            float wx = (v & 1) ? dx[i] : 1.f - dx[i];
            float wy = (v & 2) ? dy[i] : 1.f - dy[i];
            float wz = (v & 4) ? dz[i] : 1.f - dz[i];
            float w = (wx * wy) * wz;
            float2 f = unpack16(fv[i][v]);
            ax = fmaf(f.x, w, ax);
            ay = fmaf(f.y, w, ay);
        }
        __builtin_nontemporal_store(packf2(ax, ay), scl + nn[i]);
    }
}

// Fused kernel for levels lstart..15 (level-major block order keeps L2 locality)
__global__ __launch_bounds__(256)
void fused_levels(const float* __restrict__ x, const u32* __restrict__ Wh,
                  const u32x2* __restrict__ Gp, const u32x4* __restrict__ Gq,
                  u32* __restrict__ scratch,
                  ScaleArgs sc, int N, int TOT, int BPL, int lstart)
{
    int li = blockIdx.x / BPL;
    int lvl = li + lstart;
    int t = (blockIdx.x - li * BPL) * blockDim.x + threadIdx.x;
    if (t >= TOT) return;
    float scale = sc.s[lvl];
    u32* scl = scratch + (size_t)lvl * (size_t)N;

    switch (lvl) {   // block-uniform
        case 2: dense_body<DD2>(x, Gp + PO2, scl, scale, N, TOT, t); break;
        case 3: dense16_body<DD3>(x, Gq + QO3, scl, scale, N, TOT, t); break;
        case 4: dense16_body<DD4>(x, Gq + QO4, scl, scale, N, TOT, t); break;
        case 5: dense_body<DD5>(x, Gp + PO5, scl, scale, N, TOT, t); break;
        default:
            hash_body(x, Wh + (size_t)(lvl - 6) * TBLN, scl, scale, N, TOT, t);
            break;
    }
}

// LDS-staged transpose: load 256 pts x 16 levels coalesced, emit 1KB-contiguous
// full-line NT stores per wave.
__global__ __launch_bounds__(256)
void transpose_kernel(const u32* __restrict__ sc, float* __restrict__ out, int N)
{
    __shared__ u32 lds[16][257];
    int P0 = blockIdx.x * 256;
    int t = threadIdx.x;
    #pragma unroll
    for (int l = 0; l < NLEV; ++l) {
        int n = P0 + t;
        if (n < N) lds[l][t] = __builtin_nontemporal_load(sc + (size_t)l * N + n);
    }
    __syncthreads();
    int w = t >> 6, l6 = t & 63;
    #pragma unroll
    for (int k = 0; k < 8; ++k) {
        int p = w * 64 + k * 8 + (l6 >> 3);
        int c = l6 & 7;                       // chunk covers levels 2c, 2c+1
        if (P0 + p < N) {
            float2 f0 = unpack16(lds[2 * c][p]);
            float2 f1 = unpack16(lds[2 * c + 1][p]);
            f32x4 v = { f0.x, f0.y, f1.x, f1.y };
            __builtin_nontemporal_store(v,
                reinterpret_cast<f32x4*>(out + (size_t)(P0 + p) * 32u + (size_t)c * 4u));
        }
    }
}

// ---------------- fallback (round-1 kernel, known-good, f32 exact) ----------
__global__ __launch_bounds__(256)
void hashenc_fallback(const float* __restrict__ x, const float* __restrict__ W,
                      float* __restrict__ out, ScaleArgs sc, int N)
{
    int n = blockIdx.x * blockDim.x + threadIdx.x;
    if (n >= N) return;
    float px = x[(size_t)n * 3 + 0];
    float py = x[(size_t)n * 3 + 1];
    float pz = x[(size_t)n * 3 + 2];
    float acc[2 * NLEV];
    #pragma unroll
    for (int l = 0; l < NLEV; ++l) {
        float s = sc.s[l];
        float ux = px * s, uy = py * s, uz = pz * s;
        int ix = (int)ux, iy = (int)uy, iz = (int)uz;
        float dx = ux - (float)ix, dy = uy - (float)iy, dz = uz - (float)iz;
        unsigned a0 = (unsigned)ix;
        unsigned a1 = (unsigned)iy * PR1;
        unsigned a2 = (unsigned)iz * PR2;
        unsigned b0 = a0 + 1u, b1 = a1 + PR1, b2 = a2 + PR2;
        const float* Wl = W + (size_t)l * TBLN * 2u;
        float ax = 0.f, ay = 0.f;
        #pragma unroll
        for (int v = 0; v < 8; ++v) {
            unsigned h = ((v & 1) ? b0 : a0) ^ ((v & 2) ? b1 : a1) ^ ((v & 4) ? b2 : a2);
            h &= TMASK;
            float wx = (v & 1) ? dx : 1.f - dx;
            float wy = (v & 2) ? dy : 1.f - dy;
            float wz = (v & 4) ? dz : 1.f - dz;
            float w = (wx * wy) * wz;
            const float2 fvv = *reinterpret_cast<const float2*>(Wl + (size_t)h * 2u);
            ax = fmaf(fvv.x, w, ax);
            ay = fmaf(fvv.y, w, ay);
        }
        acc[2 * l + 0] = ax;
        acc[2 * l + 1] = ay;
    }
    float4* o = reinterpret_cast<float4*>(out + (size_t)n * (2 * NLEV));
    #pragma unroll
    for (int j = 0; j < 8; ++j)
        o[j] = make_float4(acc[4 * j + 0], acc[4 * j + 1], acc[4 * j + 2], acc[4 * j + 3]);
}

extern "C" void kernel_launch(void* const* d_in, const int* in_sizes, int n_in,
                              void* d_out, int out_size, void* d_ws, size_t ws_size,
                              hipStream_t stream) {
    const float* x = (const float*)d_in[0];
    const float* W = (const float*)d_in[1];
    float* out = (float*)d_out;
    int N = in_sizes[0] / 3;

    // numpy-exact scales
    ScaleArgs sc;
    double b = exp((log(2048.0) - log(16.0)) / 16.0);
    for (int l = 0; l < NLEV; ++l) {
        double p;
        switch (l) {
            case 0: p = 1.0; break;
            case 1: p = b;   break;
            case 2: p = b * b; break;
            default: p = pow(b, (double)l); break;
        }
        sc.s[l] = (float)(16.0 * p);
    }

    // workspace layout (u32): [Wh 10 tables][Gp 2,5][Gq 3,4][Gu 0,1,2][scratch]
    size_t wh_u32 = (size_t)(NLEV - 6) * TBLN;        // 21.0 MB
    size_t gp_u32 = (size_t)GPTOT2 * 2u;              // 3.6 MB
    size_t gq_u32 = (size_t)GQTOT * 4u;               // 3.6 MB
    size_t gu_u32 = (size_t)GUTOT;                    // 191 KB
    size_t scr_u32 = (size_t)NLEV * (size_t)N;        // 128 MB
    size_t need = (wh_u32 + gp_u32 + gq_u32 + gu_u32 + scr_u32) * sizeof(u32); // ~156.3 MB

    if (ws_size >= need) {
        u32* Wh = (u32*)d_ws;
        u32x2* Gp = reinterpret_cast<u32x2*>(Wh + wh_u32);
        u32x4* Gq = reinterpret_cast<u32x4*>(Wh + wh_u32 + gp_u32);
        u32* Gu = Wh + wh_u32 + gp_u32 + gq_u32;
        u32* scratch = Gu + gu_u32;

        // level-2 dynamic LDS: 31^3 u32 = 119164 B (>64KB static limit)
        size_t l2_lds_bytes = (size_t)DU2 * DU2 * DU2 * sizeof(u32);
        bool lvl2_lds = (hipFuncSetAttribute(
                             (const void*)&lds_level_dyn<DU2>,
                             hipFuncAttributeMaxDynamicSharedMemorySize,
                             (int)l2_lds_bytes) == hipSuccess);

        // fp16 tables for hash levels 6..15
        int np4 = (int)(wh_u32 / 4);
        hipLaunchKernelGGL(convert_w, dim3((np4 + 255) / 256), dim3(256), 0, stream,
                           W + (size_t)6 * TBLN * 2u, Wh, np4);

        // unpaired LDS grids for levels 0,1,2
        {
            int P0c = DU0 * DU0 * DU0;
            hipLaunchKernelGGL(build_unpaired, dim3((P0c + 255) / 256), dim3(256), 0, stream,
                               W + 0, Gu + GU0, DU0, P0c);
            int P1c = DU1 * DU1 * DU1;
            hipLaunchKernelGGL(build_unpaired, dim3((P1c + 255) / 256), dim3(256), 0, stream,
                               W + (size_t)1 * TBLN * 2u, Gu + GU1, DU1, P1c);
            int P2c = DU2 * DU2 * DU2;
            hipLaunchKernelGGL(build_unpaired, dim3((P2c + 255) / 256), dim3(256), 0, stream,
                               W + (size_t)2 * TBLN * 2u, Gu + GU2, DU2, P2c);
        }

        // x-pair grids: level 2 (fallback) and level 5
        {
            int P2 = (DD2 - 1) * DD2 * DD2;
            hipLaunchKernelGGL(build_dense, dim3((P2 + 255) / 256), dim3(256), 0, stream,
                               W + (size_t)2 * TBLN * 2u, Gp + PO2, DD2, P2);
            int P5 = (DD5 - 1) * DD5 * DD5;
            hipLaunchKernelGGL(build_dense, dim3((P5 + 255) / 256), dim3(256), 0, stream,
                               W + (size_t)5 * TBLN * 2u, Gp + PO5, DD5, P5);
        }

        // xy-quad grids: levels 3,4
        {
            int P3 = DD3 * (DD3 - 1) * (DD3 - 1);
            hipLaunchKernelGGL(build_dense16, dim3((P3 + 255) / 256), dim3(256), 0, stream,
                               W + (size_t)3 * TBLN * 2u, Gq + QO3, DD3, P3);
            int P4 = DD4 * (DD4 - 1) * (DD4 - 1);
            hipLaunchKernelGGL(build_dense16, dim3((P4 + 255) / 256), dim3(256), 0, stream,
                               W + (size_t)4 * TBLN * 2u, Gq + QO4, DD4, P4);
        }

        // levels 0,1 via static LDS grids (zero L2 gather slots)
        {
            int blocks = (N + 256 * NPTL - 1) / (256 * NPTL);
            hipLaunchKernelGGL(lds_level<DU0>, dim3(blocks), dim3(256), 0, stream,
                               x, Gu + GU0, scratch + 0, sc.s[0], N);
            hipLaunchKernelGGL(lds_level<DU1>, dim3(blocks), dim3(256), 0, stream,
                               x, Gu + GU1, scratch + (size_t)N, sc.s[1], N);
        }

        // level 2 via dynamic LDS if available
        if (lvl2_lds) {
            int blocks = (N + 512 * NPTL2 - 1) / (512 * NPTL2);
            hipLaunchKernelGGL(lds_level_dyn<DU2>, dim3(blocks), dim3(512),
                               l2_lds_bytes, stream,
                               x, Gu + GU2, scratch + (size_t)2 * N, sc.s[2], N);
        }

        // remaining levels fused (level-major, strided batching)
        int lstart = lvl2_lds ? 3 : 2;
        int TOT = (N + NPT - 1) / NPT;
        int BPL = (TOT + 255) / 256;
        hipLaunchKernelGGL(fused_levels, dim3((16 - lstart) * BPL), dim3(256), 0, stream,
                           x, Wh, Gp, Gq, scratch, sc, N, TOT, BPL, lstart);

        int gt = (N + 255) / 256;
        hipLaunchKernelGGL(transpose_kernel, dim3(gt), dim3(256), 0, stream,
                           scratch, out, N);
    } else {
        int grid = (N + 255) / 256;
        hipLaunchKernelGGL(hashenc_fallback, dim3(grid), dim3(256), 0, stream,
                           x, W, out, sc, N);
    }
}

// Round 13
// 581.929 us; speedup vs baseline: 1.1020x; 1.0431x over previous
//
#include <hip/hip_runtime.h>
#include <hip/hip_fp16.h>
#include <math.h>

#define NLEV 16
#define TBLN (1u << 19)
#define TMASK (TBLN - 1u)
#define NPT 4             // points per thread in fused level kernel (strided)
#define NPTL 16           // points per thread in LDS level kernels
#define NPTL2 8           // points per thread in dynamic LDS level-2 kernel
#define PR1 2654435761u
#define PR2 805459861u

typedef float f32x4 __attribute__((ext_vector_type(4)));
typedef unsigned int u32;
typedef unsigned int u32x2 __attribute__((ext_vector_type(2)));
typedef unsigned int u32x4 __attribute__((ext_vector_type(4)));

struct ScaleArgs { float s[NLEV]; };

// ---- compile-time geometry ----
// LDS levels 0,1,2: unpaired u32 grids D^3
#define DU0 18
#define DU1 23
#define DU2 31
#define GU0 0
#define GU1 5832
#define GU2 17999
#define GUTOT 47790
// x-pair 8B grids: level 2 (fallback) and level 5
#define DD2 31
#define DD5 75
#define PO2 0
#define PO5 28830
#define GPTOT2 445080
// xy-quad 16B grids: levels 3,4
#define DD3 41
#define DD4 55
#define QO3 0
#define QO4 65600
#define GQTOT 225980
// build_all segment offsets (work items)
#define NP4 1310720        /* convert: (10*TBLN)/4 */
#define B1 1310720
#define B2 1316552         /* +18^3 */
#define B3 1328719         /* +23^3 */
#define B4 1358510         /* +31^3 */
#define B5 1387340         /* +28830 dense l2 */
#define B6 1803590         /* +416250 dense l5 */
#define B7 1869190         /* +65600 q l3 */
#define BT 2029570         /* +160380 q l4 */

static __device__ __forceinline__ u32 packf2(float a, float b) {
    __half2 h = __floats2half2_rn(a, b);
    return __builtin_bit_cast(u32, h);
}
static __device__ __forceinline__ float2 unpack16(u32 u) {
    __half2 h = __builtin_bit_cast(__half2, u);
    return __half22float2(h);
}
static __device__ __forceinline__ u32 sel4(u32x4 P, u32 idx) {
    u32 s0 = (idx & 1u) ? P.y : P.x;
    u32 s1 = (idx & 1u) ? P.w : P.z;
    return (idx & 2u) ? s1 : s0;
}

// ---- build item bodies (device helpers, shared by build_all) ----
static __device__ __forceinline__ void conv_item(const float* __restrict__ W,
                                                 u32* __restrict__ Wh, int i)
{
    const f32x4* src = reinterpret_cast<const f32x4*>(W) + (size_t)i * 2;
    f32x4 A = __builtin_nontemporal_load(src);
    f32x4 B = __builtin_nontemporal_load(src + 1);
    u32x4 o = { packf2(A.x, A.y), packf2(A.z, A.w),
                packf2(B.x, B.y), packf2(B.z, B.w) };
    __builtin_nontemporal_store(o, reinterpret_cast<u32x4*>(Wh) + i);
}
static __device__ __forceinline__ void unp_item(const float* __restrict__ Wlf,
                                                u32* __restrict__ Gu, int D, int v)
{
    int ix = v % D;
    int rest = v / D;
    int iy = rest % D;
    int iz = rest / D;
    u32 h = (((u32)iy * PR1) ^ ((u32)iz * PR2) ^ (u32)ix) & TMASK;
    float2 f = *reinterpret_cast<const float2*>(Wlf + (size_t)h * 2u);
    Gu[v] = packf2(f.x, f.y);
}
static __device__ __forceinline__ void dens_item(const float* __restrict__ Wlf,
                                                 u32x2* __restrict__ Gpl, int D, int v)
{
    int Dx = D - 1;
    int ix = v % Dx;
    int rest = v / Dx;
    int iy = rest % D;
    int iz = rest / D;
    u32 e = ((u32)iy * PR1) ^ ((u32)iz * PR2);
    u32 h0 = (e ^ (u32)ix) & TMASK;
    u32 h1 = (e ^ (u32)(ix + 1)) & TMASK;
    float2 f0 = *reinterpret_cast<const float2*>(Wlf + (size_t)h0 * 2u);
    float2 f1 = *reinterpret_cast<const float2*>(Wlf + (size_t)h1 * 2u);
    u32x2 o = { packf2(f0.x, f0.y), packf2(f1.x, f1.y) };
    Gpl[v] = o;
}
static __device__ __forceinline__ void dens16_item(const float* __restrict__ Wlf,
                                                   u32x4* __restrict__ Gql, int D, int v)
{
    int Dx = D - 1;
    int ix = v % Dx;
    int rest = v / Dx;
    int iy = rest % Dx;
    int iz = rest / Dx;
    u32 ey0 = ((u32)iy * PR1) ^ ((u32)iz * PR2);
    u32 ey1 = ((u32)(iy + 1) * PR1) ^ ((u32)iz * PR2);
    u32 h00 = (ey0 ^ (u32)ix) & TMASK;
    u32 h10 = (ey0 ^ (u32)(ix + 1)) & TMASK;
    u32 h01 = (ey1 ^ (u32)ix) & TMASK;
    u32 h11 = (ey1 ^ (u32)(ix + 1)) & TMASK;
    float2 f00 = *reinterpret_cast<const float2*>(Wlf + (size_t)h00 * 2u);
    float2 f10 = *reinterpret_cast<const float2*>(Wlf + (size_t)h10 * 2u);
    float2 f01 = *reinterpret_cast<const float2*>(Wlf + (size_t)h01 * 2u);
    float2 f11 = *reinterpret_cast<const float2*>(Wlf + (size_t)h11 * 2u);
    u32x4 o = { packf2(f00.x, f00.y), packf2(f10.x, f10.y),
                packf2(f01.x, f01.y), packf2(f11.x, f11.y) };
    Gql[v] = o;
}

// One kernel for all prep work: convert + 3 unpaired grids + 2 pair grids +
// 2 quad grids. Segment ladder on global work index (boundary-block
// divergence only).
__global__ __launch_bounds__(256)
void build_all(const float* __restrict__ W, u32* __restrict__ Wh,
               u32* __restrict__ Gu, u32x2* __restrict__ Gp, u32x4* __restrict__ Gq)
{
    int g = blockIdx.x * blockDim.x + threadIdx.x;
    if (g < B1)      conv_item(W + (size_t)6 * TBLN * 2u, Wh, g);
    else if (g < B2) unp_item(W, Gu + GU0, DU0, g - B1);
    else if (g < B3) unp_item(W + (size_t)1 * TBLN * 2u, Gu + GU1, DU1, g - B2);
    else if (g < B4) unp_item(W + (size_t)2 * TBLN * 2u, Gu + GU2, DU2, g - B3);
    else if (g < B5) dens_item(W + (size_t)2 * TBLN * 2u, Gp + PO2, DD2, g - B4);
    else if (g < B6) dens_item(W + (size_t)5 * TBLN * 2u, Gp + PO5, DD5, g - B5);
    else if (g < B7) dens16_item(W + (size_t)3 * TBLN * 2u, Gq + QO3, DD3, g - B6);
    else if (g < BT) dens16_item(W + (size_t)4 * TBLN * 2u, Gq + QO4, DD4, g - B7);
}

// shared trilinear body for LDS-grid kernels
template<int D>
static __device__ __forceinline__ u32 lds_interp(const u32* g, float ux, float uy, float uz)
{
    int ix = (int)ux, iy = (int)uy, iz = (int)uz;
    float dx = ux - (float)ix, dy = uy - (float)iy, dz = uz - (float)iz;
    int b = (iz * D + iy) * D + ix;
    u32 c0 = g[b],             c1 = g[b + 1];
    u32 c2 = g[b + D],         c3 = g[b + D + 1];
    u32 c4 = g[b + D * D],     c5 = g[b + D * D + 1];
    u32 c6 = g[b + D * D + D], c7 = g[b + D * D + D + 1];
    float wxl = 1.f - dx, wxh = dx;
    float wyl = 1.f - dy, wyh = dy;
    float wzl = 1.f - dz, wzh = dz;
    float ax = 0.f, ay = 0.f;
    float2 f;
    f = unpack16(c0); { float w = (wxl * wyl) * wzl; ax = fmaf(f.x, w, ax); ay = fmaf(f.y, w, ay); }
    f = unpack16(c1); { float w = (wxh * wyl) * wzl; ax = fmaf(f.x, w, ax); ay = fmaf(f.y, w, ay); }
    f = unpack16(c2); { float w = (wxl * wyh) * wzl; ax = fmaf(f.x, w, ax); ay = fmaf(f.y, w, ay); }
    f = unpack16(c3); { float w = (wxh * wyh) * wzl; ax = fmaf(f.x, w, ax); ay = fmaf(f.y, w, ay); }
    f = unpack16(c4); { float w = (wxl * wyl) * wzh; ax = fmaf(f.x, w, ax); ay = fmaf(f.y, w, ay); }
    f = unpack16(c5); { float w = (wxh * wyl) * wzh; ax = fmaf(f.x, w, ax); ay = fmaf(f.y, w, ay); }
    f = unpack16(c6); { float w = (wxl * wyh) * wzh; ax = fmaf(f.x, w, ax); ay = fmaf(f.y, w, ay); }
    f = unpack16(c7); { float w = (wxh * wyh) * wzh; ax = fmaf(f.x, w, ax); ay = fmaf(f.y, w, ay); }
    return packf2(ax, ay);
}

// ---- merged dual-grid LDS kernel (levels 0 AND 1; x read once) ----
// dynamic LDS = (18^3 + 23^3)*4 = 71,996 B
__global__ __launch_bounds__(512)
void lds_level01(const float* __restrict__ x, const u32* __restrict__ Gu,
                 u32* __restrict__ scratch, float s0, float s1, int N)
{
    extern __shared__ u32 g[];
    u32* g0 = g;                       // 5832
    u32* g1 = g + DU0 * DU0 * DU0;     // 12167
    for (int i = threadIdx.x; i < DU0 * DU0 * DU0; i += 512) g0[i] = Gu[GU0 + i];
    for (int i = threadIdx.x; i < DU1 * DU1 * DU1; i += 512) g1[i] = Gu[GU1 + i];
    __syncthreads();

    int base = blockIdx.x * (512 * NPTL);
    #pragma unroll 4
    for (int i = 0; i < NPTL; ++i) {
        int n = base + i * 512 + (int)threadIdx.x;
        if (n < N) {
            float px = __builtin_nontemporal_load(&x[(size_t)n * 3 + 0]);
            float py = __builtin_nontemporal_load(&x[(size_t)n * 3 + 1]);
            float pz = __builtin_nontemporal_load(&x[(size_t)n * 3 + 2]);
            __builtin_nontemporal_store(
                lds_interp<DU0>(g0, px * s0, py * s0, pz * s0), scratch + n);
            __builtin_nontemporal_store(
                lds_interp<DU1>(g1, px * s1, py * s1, pz * s1), scratch + (size_t)N + n);
        }
    }
}

// ---- fallback static-LDS level kernels (if dyn-LDS attribute fails) ----
template<int D>
__global__ __launch_bounds__(256)
void lds_level(const float* __restrict__ x, const u32* __restrict__ Gu,
               u32* __restrict__ scl, float scale, int N)
{
    __shared__ u32 g[D * D * D];
    for (int i = threadIdx.x; i < D * D * D; i += 256) g[i] = Gu[i];
    __syncthreads();

    int base = blockIdx.x * (256 * NPTL);
    #pragma unroll 4
    for (int i = 0; i < NPTL; ++i) {
        int n = base + i * 256 + (int)threadIdx.x;
        if (n < N) {
            float px = __builtin_nontemporal_load(&x[(size_t)n * 3 + 0]);
            float py = __builtin_nontemporal_load(&x[(size_t)n * 3 + 1]);
            float pz = __builtin_nontemporal_load(&x[(size_t)n * 3 + 2]);
            __builtin_nontemporal_store(
                lds_interp<D>(g, px * scale, py * scale, pz * scale), scl + n);
        }
    }
}

// ---- dynamic-LDS level-2 kernel (31^3 u32 = 119KB) ----
template<int D>
__global__ __launch_bounds__(512)
void lds_level_dyn(const float* __restrict__ x, const u32* __restrict__ Gu,
                   u32* __restrict__ scl, float scale, int N)
{
    extern __shared__ u32 g[];
    for (int i = threadIdx.x; i < D * D * D; i += 512) g[i] = Gu[i];
    __syncthreads();

    int base = blockIdx.x * (512 * NPTL2);
    #pragma unroll 4
    for (int i = 0; i < NPTL2; ++i) {
        int n = base + i * 512 + (int)threadIdx.x;
        if (n < N) {
            float px = __builtin_nontemporal_load(&x[(size_t)n * 3 + 0]);
            float py = __builtin_nontemporal_load(&x[(size_t)n * 3 + 1]);
            float pz = __builtin_nontemporal_load(&x[(size_t)n * 3 + 2]);
            __builtin_nontemporal_store(
                lds_interp<D>(g, px * scale, py * scale, pz * scale), scl + n);
        }
    }
}

// ---- fused-kernel per-level bodies (strided batching, measured best) ----

template<int D>
static __device__ __forceinline__ void dense_body(
    const float* __restrict__ x, const u32x2* __restrict__ Gp,
    u32* __restrict__ scl, float scale, int N, int TOT, int t)
{
    constexpr int Dx = D - 1;
    constexpr int zstep = D * Dx;

    int nn[NPT];
    float dx[NPT], dy[NPT], dz[NPT];
    int base[NPT];
    u32x2 P0[NPT], P1[NPT], P2[NPT], P3[NPT];

    #pragma unroll
    for (int i = 0; i < NPT; ++i) {
        int n = t + i * TOT;
        if (n > N - 1) n = N - 1;          // duplicate write of same value: benign
        nn[i] = n;
        float px = __builtin_nontemporal_load(&x[(size_t)n * 3 + 0]);
        float py = __builtin_nontemporal_load(&x[(size_t)n * 3 + 1]);
        float pz = __builtin_nontemporal_load(&x[(size_t)n * 3 + 2]);
        float ux = px * scale, uy = py * scale, uz = pz * scale;
        int ix = (int)ux, iy = (int)uy, iz = (int)uz;
        dx[i] = ux - (float)ix;
        dy[i] = uy - (float)iy;
        dz[i] = uz - (float)iz;
        base[i] = (iz * D + iy) * Dx + ix;
    }

    #pragma unroll
    for (int i = 0; i < NPT; ++i) {
        int b = base[i];
        P0[i] = Gp[b];
        P1[i] = Gp[b + Dx];
        P2[i] = Gp[b + zstep];
        P3[i] = Gp[b + zstep + Dx];
    }

    #pragma unroll
    for (int i = 0; i < NPT; ++i) {
        float ax = 0.f, ay = 0.f;
        float wxl = 1.f - dx[i], wxh = dx[i];
        float wyl = 1.f - dy[i], wyh = dy[i];
        float wzl = 1.f - dz[i], wzh = dz[i];
        {
            float2 f0 = unpack16(P0[i].x), f1 = unpack16(P0[i].y);
            float w0 = (wxl * wyl) * wzl, w1 = (wxh * wyl) * wzl;
            ax = fmaf(f0.x, w0, ax); ay = fmaf(f0.y, w0, ay);
            ax = fmaf(f1.x, w1, ax); ay = fmaf(f1.y, w1, ay);
        }
        {
            float2 f0 = unpack16(P1[i].x), f1 = unpack16(P1[i].y);
            float w0 = (wxl * wyh) * wzl, w1 = (wxh * wyh) * wzl;
            ax = fmaf(f0.x, w0, ax); ay = fmaf(f0.y, w0, ay);
            ax = fmaf(f1.x, w1, ax); ay = fmaf(f1.y, w1, ay);
        }
        {
            float2 f0 = unpack16(P2[i].x), f1 = unpack16(P2[i].y);
            float w0 = (wxl * wyl) * wzh, w1 = (wxh * wyl) * wzh;
            ax = fmaf(f0.x, w0, ax); ay = fmaf(f0.y, w0, ay);
            ax = fmaf(f1.x, w1, ax); ay = fmaf(f1.y, w1, ay);
        }
        {
            float2 f0 = unpack16(P3[i].x), f1 = unpack16(P3[i].y);
            float w0 = (wxl * wyh) * wzh, w1 = (wxh * wyh) * wzh;
            ax = fmaf(f0.x, w0, ax); ay = fmaf(f0.y, w0, ay);
            ax = fmaf(f1.x, w1, ax); ay = fmaf(f1.y, w1, ay);
        }
        __builtin_nontemporal_store(packf2(ax, ay), scl + nn[i]);
    }
}

template<int D>
static __device__ __forceinline__ void dense16_body(
    const float* __restrict__ x, const u32x4* __restrict__ Gq,
    u32* __restrict__ scl, float scale, int N, int TOT, int t)
{
    constexpr int Dx = D - 1;
    constexpr int zstep = Dx * Dx;

    int nn[NPT];
    float dx[NPT], dy[NPT], dz[NPT];
    int base[NPT];
    u32x4 Q0[NPT], Q1[NPT];

    #pragma unroll
    for (int i = 0; i < NPT; ++i) {
        int n = t + i * TOT;
        if (n > N - 1) n = N - 1;
        nn[i] = n;
        float px = __builtin_nontemporal_load(&x[(size_t)n * 3 + 0]);
        float py = __builtin_nontemporal_load(&x[(size_t)n * 3 + 1]);
        float pz = __builtin_nontemporal_load(&x[(size_t)n * 3 + 2]);
        float ux = px * scale, uy = py * scale, uz = pz * scale;
        int ix = (int)ux, iy = (int)uy, iz = (int)uz;
        dx[i] = ux - (float)ix;
        dy[i] = uy - (float)iy;
        dz[i] = uz - (float)iz;
        base[i] = (iz * Dx + iy) * Dx + ix;
    }

    #pragma unroll
    for (int i = 0; i < NPT; ++i) {
        Q0[i] = Gq[base[i]];
        Q1[i] = Gq[base[i] + zstep];
    }

    #pragma unroll
    for (int i = 0; i < NPT; ++i) {
        float ax = 0.f, ay = 0.f;
        float wxl = 1.f - dx[i], wxh = dx[i];
        float wyl = 1.f - dy[i], wyh = dy[i];
        float wzl = 1.f - dz[i], wzh = dz[i];
        float2 f;
        f = unpack16(Q0[i].x); { float w = (wxl * wyl) * wzl; ax = fmaf(f.x, w, ax); ay = fmaf(f.y, w, ay); }
        f = unpack16(Q0[i].y); { float w = (wxh * wyl) * wzl; ax = fmaf(f.x, w, ax); ay = fmaf(f.y, w, ay); }
        f = unpack16(Q0[i].z); { float w = (wxl * wyh) * wzl; ax = fmaf(f.x, w, ax); ay = fmaf(f.y, w, ay); }
        f = unpack16(Q0[i].w); { float w = (wxh * wyh) * wzl; ax = fmaf(f.x, w, ax); ay = fmaf(f.y, w, ay); }
        f = unpack16(Q1[i].x); { float w = (wxl * wyl) * wzh; ax = fmaf(f.x, w, ax); ay = fmaf(f.y, w, ay); }
        f = unpack16(Q1[i].y); { float w = (wxh * wyl) * wzh; ax = fmaf(f.x, w, ax); ay = fmaf(f.y, w, ay); }
        f = unpack16(Q1[i].z); { float w = (wxl * wyh) * wzh; ax = fmaf(f.x, w, ax); ay = fmaf(f.y, w, ay); }
        f = unpack16(Q1[i].w); { float w = (wxh * wyh) * wzh; ax = fmaf(f.x, w, ax); ay = fmaf(f.y, w, ay); }
        __builtin_nontemporal_store(packf2(ax, ay), scl + nn[i]);
    }
}

// hash: 3-way pairing (even ix -> 8B pair; ix%4==1 -> 16B chunk; else 2 scalars)
static __device__ __forceinline__ void hash_body(
    const float* __restrict__ x, const u32* __restrict__ Wl,
    u32* __restrict__ scl, float scale, int N, int TOT, int t)
{
    int nn[NPT];
    float dx[NPT], dy[NPT], dz[NPT];
    u32 a0[NPT], a1[NPT], a2[NPT];
    u32 fv[NPT][8];

    #pragma unroll
    for (int i = 0; i < NPT; ++i) {
        int n = t + i * TOT;
        if (n > N - 1) n = N - 1;
        nn[i] = n;
        float px = __builtin_nontemporal_load(&x[(size_t)n * 3 + 0]);
        float py = __builtin_nontemporal_load(&x[(size_t)n * 3 + 1]);
        float pz = __builtin_nontemporal_load(&x[(size_t)n * 3 + 2]);
        float ux = px * scale, uy = py * scale, uz = pz * scale;
        int ix = (int)ux, iy = (int)uy, iz = (int)uz;
        dx[i] = ux - (float)ix;
        dy[i] = uy - (float)iy;
        dz[i] = uz - (float)iz;
        a0[i] = (unsigned)ix;
        a1[i] = (unsigned)iy * PR1;
        a2[i] = (unsigned)iz * PR2;
    }

    #pragma unroll
    for (int i = 0; i < NPT; ++i) {
        u32 b0 = a0[i] + 1u, b1 = a1[i] + PR1, b2 = a2[i] + PR2;
        u32 E[4] = { a1[i] ^ a2[i], b1 ^ a2[i], a1[i] ^ b2, b1 ^ b2 };
        u32 par = a0[i] & 3u;
        if ((par & 1u) == 0u) {
            #pragma unroll
            for (int j = 0; j < 4; ++j) {
                u32 hl = (E[j] ^ a0[i]) & TMASK;
                u32x2 p = *reinterpret_cast<const u32x2*>(Wl + (hl & ~1u));
                fv[i][2 * j + 0] = (hl & 1u) ? p.y : p.x;
                fv[i][2 * j + 1] = (hl & 1u) ? p.x : p.y;
            }
        } else if (par == 1u) {
            #pragma unroll
            for (int j = 0; j < 4; ++j) {
                u32 hl = (E[j] ^ a0[i]) & TMASK;
                u32x4 P = *reinterpret_cast<const u32x4*>(Wl + (hl & ~3u));
                u32 il = hl & 3u;
                fv[i][2 * j + 0] = sel4(P, il);
                fv[i][2 * j + 1] = sel4(P, il ^ 3u);
            }
        } else {
            #pragma unroll
            for (int j = 0; j < 4; ++j) {
                u32 hl = (E[j] ^ a0[i]) & TMASK;
                u32 hh = (E[j] ^ b0) & TMASK;
                fv[i][2 * j + 0] = Wl[hl];
                fv[i][2 * j + 1] = Wl[hh];
            }
        }
    }

    #pragma unroll
    for (int i = 0; i < NPT; ++i) {
        float ax = 0.f, ay = 0.f;
        #pragma unroll
        for (int v = 0; v < 8; ++v) {
            float wx = (v & 1) ? dx[i] : 1.f - dx[i];
            float wy = (v & 2) ? dy[i] : 1.f - dy[i];
            float wz = (v & 4) ? dz[i] : 1.f - dz[i];
            float w = (wx * wy) * wz;
            float2 f = unpack16(fv[i][v]);
            ax = fmaf(f.x, w, ax);
            ay = fmaf(f.y, w, ay);
        }
        __builtin_nontemporal_store(packf2(ax, ay), scl + nn[i]);
    }
}

__global__ __launch_bounds__(256)
void fused_levels(const float* __restrict__ x, const u32* __restrict__ Wh,
                  const u32x2* __restrict__ Gp, const u32x4* __restrict__ Gq,
                  u32* __restrict__ scratch,
                  ScaleArgs sc, int N, int TOT, int BPL, int lstart)
{
    int li = blockIdx.x / BPL;
    int lvl = li + lstart;
    int t = (blockIdx.x - li * BPL) * blockDim.x + threadIdx.x;
    if (t >= TOT) return;
    float scale = sc.s[lvl];
    u32* scl = scratch + (size_t)lvl * (size_t)N;

    switch (lvl) {
        case 2: dense_body<DD2>(x, Gp + PO2, scl, scale, N, TOT, t); break;
        case 3: dense16_body<DD3>(x, Gq + QO3, scl, scale, N, TOT, t); break;
        case 4: dense16_body<DD4>(x, Gq + QO4, scl, scale, N, TOT, t); break;
        case 5: dense_body<DD5>(x, Gp + PO5, scl, scale, N, TOT, t); break;
        default:
            hash_body(x, Wh + (size_t)(lvl - 6) * TBLN, scl, scale, N, TOT, t);
            break;
    }
}

// LDS-staged transpose (full-line NT out writes)
__global__ __launch_bounds__(256)
void transpose_kernel(const u32* __restrict__ sc, float* __restrict__ out, int N)
{
    __shared__ u32 lds[16][257];
    int P0 = blockIdx.x * 256;
    int t = threadIdx.x;
    #pragma unroll
    for (int l = 0; l < NLEV; ++l) {
        int n = P0 + t;
        if (n < N) lds[l][t] = __builtin_nontemporal_load(sc + (size_t)l * N + n);
    }
    __syncthreads();
    int w = t >> 6, l6 = t & 63;
    #pragma unroll
    for (int k = 0; k < 8; ++k) {
        int p = w * 64 + k * 8 + (l6 >> 3);
        int c = l6 & 7;
        if (P0 + p < N) {
            float2 f0 = unpack16(lds[2 * c][p]);
            float2 f1 = unpack16(lds[2 * c + 1][p]);
            f32x4 v = { f0.x, f0.y, f1.x, f1.y };
            __builtin_nontemporal_store(v,
                reinterpret_cast<f32x4*>(out + (size_t)(P0 + p) * 32u + (size_t)c * 4u));
        }
    }
}

// ---------------- fallback (round-1 kernel, known-good, f32 exact) ----------
__global__ __launch_bounds__(256)
void hashenc_fallback(const float* __restrict__ x, const float* __restrict__ W,
                      float* __restrict__ out, ScaleArgs sc, int N)
{
    int n = blockIdx.x * blockDim.x + threadIdx.x;
    if (n >= N) return;
    float px = x[(size_t)n * 3 + 0];
    float py = x[(size_t)n * 3 + 1];
    float pz = x[(size_t)n * 3 + 2];
    float acc[2 * NLEV];
    #pragma unroll
    for (int l = 0; l < NLEV; ++l) {
        float s = sc.s[l];
        float ux = px * s, uy = py * s, uz = pz * s;
        int ix = (int)ux, iy = (int)uy, iz = (int)uz;
        float dx = ux - (float)ix, dy = uy - (float)iy, dz = uz - (float)iz;
        unsigned a0 = (unsigned)ix;
        unsigned a1 = (unsigned)iy * PR1;
        unsigned a2 = (unsigned)iz * PR2;
        unsigned b0 = a0 + 1u, b1 = a1 + PR1, b2 = a2 + PR2;
        const float* Wl = W + (size_t)l * TBLN * 2u;
        float ax = 0.f, ay = 0.f;
        #pragma unroll
        for (int v = 0; v < 8; ++v) {
            unsigned h = ((v & 1) ? b0 : a0) ^ ((v & 2) ? b1 : a1) ^ ((v & 4) ? b2 : a2);
            h &= TMASK;
            float wx = (v & 1) ? dx : 1.f - dx;
            float wy = (v & 2) ? dy : 1.f - dy;
            float wz = (v & 4) ? dz : 1.f - dz;
            float w = (wx * wy) * wz;
            const float2 fvv = *reinterpret_cast<const float2*>(Wl + (size_t)h * 2u);
            ax = fmaf(fvv.x, w, ax);
            ay = fmaf(fvv.y, w, ay);
        }
        acc[2 * l + 0] = ax;
        acc[2 * l + 1] = ay;
    }
    float4* o = reinterpret_cast<float4*>(out + (size_t)n * (2 * NLEV));
    #pragma unroll
    for (int j = 0; j < 8; ++j)
        o[j] = make_float4(acc[4 * j + 0], acc[4 * j + 1], acc[4 * j + 2], acc[4 * j + 3]);
}

extern "C" void kernel_launch(void* const* d_in, const int* in_sizes, int n_in,
                              void* d_out, int out_size, void* d_ws, size_t ws_size,
                              hipStream_t stream) {
    const float* x = (const float*)d_in[0];
    const float* W = (const float*)d_in[1];
    float* out = (float*)d_out;
    int N = in_sizes[0] / 3;

    // numpy-exact scales
    ScaleArgs sc;
    double b = exp((log(2048.0) - log(16.0)) / 16.0);
    for (int l = 0; l < NLEV; ++l) {
        double p;
        switch (l) {
            case 0: p = 1.0; break;
            case 1: p = b;   break;
            case 2: p = b * b; break;
            default: p = pow(b, (double)l); break;
        }
        sc.s[l] = (float)(16.0 * p);
    }

    // workspace layout (u32): [Wh 10 tables][Gp 2,5][Gq 3,4][Gu 0,1,2][scratch]
    size_t wh_u32 = (size_t)(NLEV - 6) * TBLN;
    size_t gp_u32 = (size_t)GPTOT2 * 2u;
    size_t gq_u32 = (size_t)GQTOT * 4u;
    size_t gu_u32 = (size_t)GUTOT;
    size_t scr_u32 = (size_t)NLEV * (size_t)N;
    size_t need = (wh_u32 + gp_u32 + gq_u32 + gu_u32 + scr_u32) * sizeof(u32); // ~156.3 MB

    if (ws_size >= need) {
        u32* Wh = (u32*)d_ws;
        u32x2* Gp = reinterpret_cast<u32x2*>(Wh + wh_u32);
        u32x4* Gq = reinterpret_cast<u32x4*>(Wh + wh_u32 + gp_u32);
        u32* Gu = Wh + wh_u32 + gp_u32 + gq_u32;
        u32* scratch = Gu + gu_u32;

        // dynamic-LDS attribute setup (host-side, deterministic per process)
        size_t l01_lds_bytes = (size_t)(DU0 * DU0 * DU0 + DU1 * DU1 * DU1) * sizeof(u32);
        bool lvl01_lds = (hipFuncSetAttribute(
                              (const void*)&lds_level01,
                              hipFuncAttributeMaxDynamicSharedMemorySize,
                              (int)l01_lds_bytes) == hipSuccess);
        size_t l2_lds_bytes = (size_t)DU2 * DU2 * DU2 * sizeof(u32);
        bool lvl2_lds = (hipFuncSetAttribute(
                             (const void*)&lds_level_dyn<DU2>,
                             hipFuncAttributeMaxDynamicSharedMemorySize,
                             (int)l2_lds_bytes) == hipSuccess);

        // single prep kernel: convert + all grids
        hipLaunchKernelGGL(build_all, dim3((BT + 255) / 256), dim3(256), 0, stream,
                           W, Wh, Gu, Gp, Gq);

        // levels 0,1 (dual-grid dyn-LDS kernel; fallback: two static kernels)
        if (lvl01_lds) {
            int blocks = (N + 512 * NPTL - 1) / (512 * NPTL);
            hipLaunchKernelGGL(lds_level01, dim3(blocks), dim3(512),
                               l01_lds_bytes, stream,
                               x, Gu, scratch, sc.s[0], sc.s[1], N);
        } else {
            int blocks = (N + 256 * NPTL - 1) / (256 * NPTL);
            hipLaunchKernelGGL(lds_level<DU0>, dim3(blocks), dim3(256), 0, stream,
                               x, Gu + GU0, scratch + 0, sc.s[0], N);
            hipLaunchKernelGGL(lds_level<DU1>, dim3(blocks), dim3(256), 0, stream,
                               x, Gu + GU1, scratch + (size_t)N, sc.s[1], N);
        }

        // level 2 via dynamic LDS if available
        if (lvl2_lds) {
            int blocks = (N + 512 * NPTL2 - 1) / (512 * NPTL2);
            hipLaunchKernelGGL(lds_level_dyn<DU2>, dim3(blocks), dim3(512),
                               l2_lds_bytes, stream,
                               x, Gu + GU2, scratch + (size_t)2 * N, sc.s[2], N);
        }

        // remaining levels fused (level-major, strided batching)
        int lstart = lvl2_lds ? 3 : 2;
        int TOT = (N + NPT - 1) / NPT;
        int BPL = (TOT + 255) / 256;
        hipLaunchKernelGGL(fused_levels, dim3((16 - lstart) * BPL), dim3(256), 0, stream,
                           x, Wh, Gp, Gq, scratch, sc, N, TOT, BPL, lstart);

        int gt = (N + 255) / 256;
        hipLaunchKernelGGL(transpose_kernel, dim3(gt), dim3(256), 0, stream,
                           scratch, out, N);
    } else {
        int grid = (N + 255) / 256;
        hipLaunchKernelGGL(hashenc_fallback, dim3(grid), dim3(256), 0, stream,
                           x, W, out, sc, N);
    }
}